// Round 5
// baseline (3310.093 us; speedup 1.0000x reference)
//
#include <hip/hip_runtime.h>

typedef unsigned short u16;
typedef unsigned int u32;

#define NN 50000
#define EE 250000
#define GG 512

typedef __bf16 bf16x8 __attribute__((ext_vector_type(8)));
typedef float  f32x4  __attribute__((ext_vector_type(4)));

__device__ __forceinline__ u16 f2bfu(float f) {
    __bf16 b = (__bf16)f; u16 u; __builtin_memcpy(&u, &b, 2); return u;
}
__device__ __forceinline__ float sigf(float x) { return 1.f / (1.f + expf(-x)); }

// ---------------------------------------------------------------------------
// Build swizzled B (We2 viewed as 1024x32, plus be2 as a 33rd K-step) in
// MFMA fragment order: Bg[kk*1024 + ct*512 + l*8 + j] = W[32*kk+8*(l>>4)+j][(l&15)+16*ct]
// ---------------------------------------------------------------------------
__global__ void prep_B(const float* __restrict__ We2, const float* __restrict__ be2,
                       u16* __restrict__ Bg) {
    int idx = blockIdx.x * blockDim.x + threadIdx.x;
    if (idx >= 33 * 1024) return;
    int kk = idx >> 10, off = idx & 1023;
    int ct = off >> 9, l = (off >> 3) & 63, j = off & 7;
    int q = l >> 4, c = l & 15, o = c + 16 * ct;
    float v;
    if (kk < 32) v = We2[(32 * kk + 8 * q + j) * 32 + o];
    else         v = be2[(8 * q + j) * 32 + o];
    Bg[idx] = f2bfu(v);
}

// ---------------------------------------------------------------------------
// Gather GRU gate weights into coalesced per-j layout:
// wta[k*32+j] = {Wih_r[j][k], Wih_z[j][k], Wih_n[j][k], Whh_r[j][k]}
// wtb[k*32+j] = {Whh_z[j][k], Whh_n[j][k]}
// ---------------------------------------------------------------------------
__global__ void prep_WT(const float* __restrict__ Wih, const float* __restrict__ Whh,
                        float4* __restrict__ wta, float2* __restrict__ wtb) {
    int t = blockIdx.x * blockDim.x + threadIdx.x;
    if (t >= 1024) return;
    int k = t >> 5, j = t & 31;
    wta[t] = make_float4(Wih[j * 32 + k], Wih[(32 + j) * 32 + k],
                         Wih[(64 + j) * 32 + k], Whh[j * 32 + k]);
    wtb[t] = make_float2(Whh[(32 + j) * 32 + k], Whh[(64 + j) * 32 + k]);
}

// ---------------------------------------------------------------------------
// t = relu(edge_attr @ We1 + be1), stored bf16 [E][32]
// ---------------------------------------------------------------------------
__global__ void prep_edges(const float* __restrict__ ea, const float* __restrict__ We1,
                           const float* __restrict__ be1, u16* __restrict__ tmat) {
    int e = blockIdx.x * blockDim.x + threadIdx.x;
    if (e >= EE) return;
    const float4* ep = (const float4*)(ea + (size_t)e * 16);
    float a[16];
#pragma unroll
    for (int i = 0; i < 4; i++) {
        float4 v = ep[i];
        a[4 * i] = v.x; a[4 * i + 1] = v.y; a[4 * i + 2] = v.z; a[4 * i + 3] = v.w;
    }
    u32 outw[16];
#pragma unroll
    for (int p = 0; p < 16; p++) {
        float acc0 = be1[2 * p], acc1 = be1[2 * p + 1];
#pragma unroll
        for (int k = 0; k < 16; k++) {
            acc0 += a[k] * We1[k * 32 + 2 * p];
            acc1 += a[k] * We1[k * 32 + 2 * p + 1];
        }
        acc0 = fmaxf(acc0, 0.f); acc1 = fmaxf(acc1, 0.f);
        outw[p] = (u32)f2bfu(acc0) | ((u32)f2bfu(acc1) << 16);
    }
    uint4* op = (uint4*)(tmat + (size_t)e * 32);
#pragma unroll
    for (int i = 0; i < 4; i++)
        op[i] = make_uint4(outw[4 * i], outw[4 * i + 1], outw[4 * i + 2], outw[4 * i + 3]);
}

// ---------------------------------------------------------------------------
// h = relu(x @ W0 + b0); write f32 state + bf16 mirror
// ---------------------------------------------------------------------------
__global__ void lin0_k(const float* __restrict__ x, const float* __restrict__ W0,
                       const float* __restrict__ b0, float* __restrict__ hf,
                       u16* __restrict__ cur) {
    int n = blockIdx.x * blockDim.x + threadIdx.x;
    if (n >= NN) return;
    const float4* xp = (const float4*)(x + (size_t)n * 32);
    float a[32];
#pragma unroll
    for (int i = 0; i < 8; i++) {
        float4 v = xp[i];
        a[4 * i] = v.x; a[4 * i + 1] = v.y; a[4 * i + 2] = v.z; a[4 * i + 3] = v.w;
    }
    float o[32];
#pragma unroll 4
    for (int c = 0; c < 32; c++) {
        float acc = b0[c];
#pragma unroll
        for (int k = 0; k < 32; k++) acc += a[k] * W0[k * 32 + c];
        o[c] = fmaxf(acc, 0.f);
    }
    float4* hp = (float4*)(hf + (size_t)n * 32);
#pragma unroll
    for (int i = 0; i < 8; i++) hp[i] = make_float4(o[4 * i], o[4 * i + 1], o[4 * i + 2], o[4 * i + 3]);
    uint4* cp = (uint4*)(cur + (size_t)n * 32);
#pragma unroll
    for (int i = 0; i < 4; i++) {
        u32 p0 = (u32)f2bfu(o[8 * i + 0]) | ((u32)f2bfu(o[8 * i + 1]) << 16);
        u32 p1 = (u32)f2bfu(o[8 * i + 2]) | ((u32)f2bfu(o[8 * i + 3]) << 16);
        u32 p2 = (u32)f2bfu(o[8 * i + 4]) | ((u32)f2bfu(o[8 * i + 5]) << 16);
        u32 p3 = (u32)f2bfu(o[8 * i + 6]) | ((u32)f2bfu(o[8 * i + 7]) << 16);
        cp[i] = make_uint4(p0, p1, p2, p3);
    }
}

// ---------------------------------------------------------------------------
// histograms
// ---------------------------------------------------------------------------
__global__ void hist_k(const int* __restrict__ ei, const int* __restrict__ batch,
                       int* __restrict__ degc, int* __restrict__ gcnt) {
    int i = blockIdx.x * blockDim.x + threadIdx.x;
    if (i < EE) atomicAdd(degc + ei[EE + i], 1);
    if (i < NN) atomicAdd(gcnt + batch[i], 1);
}

__global__ void degfin_k(const int* __restrict__ degc, float* __restrict__ dinv) {
    int n = blockIdx.x * blockDim.x + threadIdx.x;
    if (n >= NN) return;
    int c = degc[n];
    dinv[n] = 1.f / (float)(c > 0 ? c : 1);
}

// ---------------------------------------------------------------------------
// Message kernel (unchanged from passing round)
// ---------------------------------------------------------------------------
__global__ __launch_bounds__(512) void msg_k(const u16* __restrict__ cur,
                                             const u16* __restrict__ tmat,
                                             const int* __restrict__ ei,
                                             const u16* __restrict__ Bg,
                                             float* __restrict__ agg) {
    __shared__ uint4 Bl[4096];
    const uint4* Bgv = (const uint4*)Bg;
    for (int i = threadIdx.x; i < 4096; i += 512) Bl[i] = Bgv[i];
    __syncthreads();
    const u16* Bl16 = (const u16*)Bl;

    int l = threadIdx.x & 63;
    int q = l >> 4, r = l & 15;
    int wid = (blockIdx.x * blockDim.x + threadIdx.x) >> 6;
    int nw  = (gridDim.x * blockDim.x) >> 6;

    for (int tile = wid; tile < EE / 16; tile += nw) {
        int eb = tile * 16;
        int srow = ei[eb + r];
        bf16x8 sv = *reinterpret_cast<const bf16x8*>(cur + (size_t)srow * 32 + q * 8);
        float sf[8];
#pragma unroll
        for (int j = 0; j < 8; j++) sf[j] = (float)sv[j];
        const uint4* tp = reinterpret_cast<const uint4*>(tmat + (size_t)(eb + r) * 32);
        f32x4 acc0 = {0.f, 0.f, 0.f, 0.f}, acc1 = {0.f, 0.f, 0.f, 0.f};
#pragma unroll
        for (int kq = 0; kq < 4; kq++) {
            uint4 tw4 = tp[kq];
            u32 tws[4] = {tw4.x, tw4.y, tw4.z, tw4.w};
#pragma unroll
            for (int du = 0; du < 4; du++) {
                u32 w = tws[du];
#pragma unroll
                for (int hl = 0; hl < 2; hl++) {
                    int kk = kq * 8 + du * 2 + hl;
                    float tf = __uint_as_float(hl ? (w & 0xffff0000u) : (w << 16));
                    bf16x8 av;
#pragma unroll
                    for (int j = 0; j < 8; j++) av[j] = (__bf16)(tf * sf[j]);
                    bf16x8 b0 = *reinterpret_cast<const bf16x8*>(Bl16 + kk * 1024 + l * 8);
                    bf16x8 b1 = *reinterpret_cast<const bf16x8*>(Bl16 + kk * 1024 + 512 + l * 8);
                    acc0 = __builtin_amdgcn_mfma_f32_16x16x32_bf16(av, b0, acc0, 0, 0, 0);
                    acc1 = __builtin_amdgcn_mfma_f32_16x16x32_bf16(av, b1, acc1, 0, 0, 0);
                }
            }
        }
        {
            bf16x8 b0 = *reinterpret_cast<const bf16x8*>(Bg + 32 * 1024 + l * 8);
            bf16x8 b1 = *reinterpret_cast<const bf16x8*>(Bg + 32 * 1024 + 512 + l * 8);
            acc0 = __builtin_amdgcn_mfma_f32_16x16x32_bf16(sv, b0, acc0, 0, 0, 0);
            acc1 = __builtin_amdgcn_mfma_f32_16x16x32_bf16(sv, b1, acc1, 0, 0, 0);
        }
#pragma unroll
        for (int j = 0; j < 4; j++) {
            int d = ei[EE + eb + 4 * q + j];
            atomicAdd(agg + (size_t)d * 32 + r,      acc0[j]);
            atomicAdd(agg + (size_t)d * 32 + 16 + r, acc1[j]);
        }
    }
}

// ---------------------------------------------------------------------------
// Node update, tiled f32 GEMM style. Block = 256 threads = 64 nodes.
// LDS: hT[32k][68n], mT[32k][68n], Wroot, wta(float4/j), wtb(float2/j).
// Phase B: m = relu(bconv + agg*dinv + h@Wroot)   (thread: 2 nodes x 4 cols)
// Phase C: gates GEMM + GRU epilogue               (thread: 4 nodes x 2 j)
// ---------------------------------------------------------------------------
__global__ __launch_bounds__(256, 2) void node_update_t(
        float* __restrict__ hf, u16* __restrict__ cur,
        const float* __restrict__ agg, const float* __restrict__ dinv,
        const float* __restrict__ Wroot, const float* __restrict__ bconv,
        const float4* __restrict__ wta_g, const float2* __restrict__ wtb_g,
        const float* __restrict__ bih, const float* __restrict__ bhh) {
    __shared__ float  sh_hT[32][68];
    __shared__ float  sh_mT[32][68];
    __shared__ float  wroot_l[1024];
    __shared__ float4 wta_l[1024];
    __shared__ float2 wtb_l[1024];

    const int t  = threadIdx.x;
    const int nb = blockIdx.x * 64;

    // ---- stage weights + h tile ----
    ((float4*)wroot_l)[t] = ((const float4*)Wroot)[t];
#pragma unroll
    for (int i = 0; i < 4; i++) wta_l[t + 256 * i] = wta_g[t + 256 * i];
#pragma unroll
    for (int i = 0; i < 2; i++)
        ((float4*)wtb_l)[t + 256 * i] = ((const float4*)wtb_g)[t + 256 * i];
#pragma unroll
    for (int i = 0; i < 2; i++) {
        int fi = t + 256 * i;              // 0..511
        int row = fi >> 3, c4 = (fi & 7) * 4;
        int ncl = nb + row; if (ncl > NN - 1) ncl = NN - 1;
        float4 v = *(const float4*)(hf + (size_t)ncl * 32 + c4);
        sh_hT[c4 + 0][row] = v.x; sh_hT[c4 + 1][row] = v.y;
        sh_hT[c4 + 2][row] = v.z; sh_hT[c4 + 3][row] = v.w;
    }
    __syncthreads();

    // ---- Phase B: mv ----
    {
        const int n0p = (t >> 3) * 2;      // node pair base (0..62)
        const int c0  = (t & 7) * 4;       // col base
        float4 bcv = *(const float4*)(bconv + c0);
        float mm[2][4];
#pragma unroll
        for (int i = 0; i < 2; i++) {
            int n = nb + n0p + i; if (n > NN - 1) n = NN - 1;
            float4 ag = *(const float4*)(agg + (size_t)n * 32 + c0);
            float di = dinv[n];
            mm[i][0] = bcv.x + ag.x * di; mm[i][1] = bcv.y + ag.y * di;
            mm[i][2] = bcv.z + ag.z * di; mm[i][3] = bcv.w + ag.w * di;
        }
#pragma unroll
        for (int k = 0; k < 32; k++) {
            float2 hh = *(const float2*)&sh_hT[k][n0p];
            float4 wr = *(const float4*)&wroot_l[k * 32 + c0];
            mm[0][0] += hh.x * wr.x; mm[0][1] += hh.x * wr.y;
            mm[0][2] += hh.x * wr.z; mm[0][3] += hh.x * wr.w;
            mm[1][0] += hh.y * wr.x; mm[1][1] += hh.y * wr.y;
            mm[1][2] += hh.y * wr.z; mm[1][3] += hh.y * wr.w;
        }
#pragma unroll
        for (int p = 0; p < 4; p++) {
            float2 st = make_float2(fmaxf(mm[0][p], 0.f), fmaxf(mm[1][p], 0.f));
            *(float2*)&sh_mT[c0 + p][n0p] = st;
        }
    }
    __syncthreads();

    // ---- Phase C: gates GEMM + epilogue ----
    const int n0 = (t >> 4) * 4;           // 0,4,...,60
    const int j0 = (t & 15) * 2;           // 0,2,...,30

    float air[4][2], aiz[4][2], ain[4][2], ahr[4][2], ahz[4][2], ahn[4][2];
#pragma unroll
    for (int i = 0; i < 4; i++)
#pragma unroll
        for (int jj = 0; jj < 2; jj++) {
            air[i][jj] = 0.f; aiz[i][jj] = 0.f; ain[i][jj] = 0.f;
            ahr[i][jj] = 0.f; ahz[i][jj] = 0.f; ahn[i][jj] = 0.f;
        }

#pragma unroll
    for (int k = 0; k < 32; k++) {
        float4 hv = *(const float4*)&sh_hT[k][n0];
        float4 mv = *(const float4*)&sh_mT[k][n0];
        float4 wa0 = wta_l[k * 32 + j0];
        float4 wa1 = wta_l[k * 32 + j0 + 1];
        float4 wb  = *(const float4*)&wtb_l[k * 32 + j0];
        float hv_a[4] = {hv.x, hv.y, hv.z, hv.w};
        float mv_a[4] = {mv.x, mv.y, mv.z, mv.w};
#pragma unroll
        for (int i = 0; i < 4; i++) {
            air[i][0] = fmaf(mv_a[i], wa0.x, air[i][0]);
            aiz[i][0] = fmaf(mv_a[i], wa0.y, aiz[i][0]);
            ain[i][0] = fmaf(mv_a[i], wa0.z, ain[i][0]);
            ahr[i][0] = fmaf(hv_a[i], wa0.w, ahr[i][0]);
            ahz[i][0] = fmaf(hv_a[i], wb.x,  ahz[i][0]);
            ahn[i][0] = fmaf(hv_a[i], wb.y,  ahn[i][0]);
            air[i][1] = fmaf(mv_a[i], wa1.x, air[i][1]);
            aiz[i][1] = fmaf(mv_a[i], wa1.y, aiz[i][1]);
            ain[i][1] = fmaf(mv_a[i], wa1.z, ain[i][1]);
            ahr[i][1] = fmaf(hv_a[i], wa1.w, ahr[i][1]);
            ahz[i][1] = fmaf(hv_a[i], wb.z,  ahz[i][1]);
            ahn[i][1] = fmaf(hv_a[i], wb.w,  ahn[i][1]);
        }
    }

    float bir[2] = {bih[j0],      bih[j0 + 1]};
    float biz[2] = {bih[32 + j0], bih[32 + j0 + 1]};
    float bin[2] = {bih[64 + j0], bih[64 + j0 + 1]};
    float bhr[2] = {bhh[j0],      bhh[j0 + 1]};
    float bhz[2] = {bhh[32 + j0], bhh[32 + j0 + 1]};
    float bhn[2] = {bhh[64 + j0], bhh[64 + j0 + 1]};

#pragma unroll
    for (int i = 0; i < 4; i++) {
        int n = nb + n0 + i;
        float out2[2];
#pragma unroll
        for (int jj = 0; jj < 2; jj++) {
            float ho = sh_hT[j0 + jj][n0 + i];
            float r  = sigf(air[i][jj] + ahr[i][jj] + bir[jj] + bhr[jj]);
            float z  = sigf(aiz[i][jj] + ahz[i][jj] + biz[jj] + bhz[jj]);
            float nn = tanhf(ain[i][jj] + bin[jj] + r * (ahn[i][jj] + bhn[jj]));
            out2[jj] = (1.f - z) * nn + z * ho;
        }
        if (n < NN) {
            *(float2*)(hf + (size_t)n * 32 + j0) = make_float2(out2[0], out2[1]);
            u32 pk = (u32)f2bfu(out2[0]) | ((u32)f2bfu(out2[1]) << 16);
            *(u32*)(cur + (size_t)n * 32 + j0) = pk;
        }
    }
}

__global__ void pool_k(const float* __restrict__ hf, const int* __restrict__ batch,
                       float* __restrict__ gsum) {
    int n = blockIdx.x * blockDim.x + threadIdx.x;
    if (n >= NN) return;
    int g = batch[n];
#pragma unroll 8
    for (int o = 0; o < 32; o++) atomicAdd(gsum + g * 32 + o, hf[(size_t)n * 32 + o]);
}

// ---------------------------------------------------------------------------
// Heads: OUTPUT IS FLOAT32
// ---------------------------------------------------------------------------
__global__ void head_k(const float* __restrict__ gsum, const int* __restrict__ gcnt,
                       const float* __restrict__ W1a, const float* __restrict__ b1a,
                       const float* __restrict__ W1b, const float* __restrict__ b1b,
                       const float* __restrict__ W2a, const float* __restrict__ b2a,
                       const float* __restrict__ W2b, const float* __restrict__ b2b,
                       float* __restrict__ dout) {
    int g = blockIdx.x * blockDim.x + threadIdx.x;
    if (g >= GG) return;
    int c0 = gcnt[g];
    float rc = 1.f / (float)(c0 > 0 ? c0 : 1);
    float p[32];
#pragma unroll
    for (int i = 0; i < 32; i++) p[i] = gsum[g * 32 + i] * rc;
    float lab = b1b[0];
#pragma unroll 4
    for (int c = 0; c < 32; c++) {
        float acc = b1a[c];
#pragma unroll
        for (int k = 0; k < 32; k++) acc += p[k] * W1a[k * 32 + c];
        lab += fmaxf(acc, 0.f) * W1b[c];
    }
    float d0 = b2b[0], d1 = b2b[1];
#pragma unroll 4
    for (int c = 0; c < 32; c++) {
        float acc = b2a[c];
#pragma unroll
        for (int k = 0; k < 32; k++) acc += p[k] * W2a[k * 32 + c];
        float t = fmaxf(acc, 0.f);
        d0 += t * W2b[c * 2];
        d1 += t * W2b[c * 2 + 1];
    }
    float mx = fmaxf(d0, d1);
    float ls = mx + logf(expf(d0 - mx) + expf(d1 - mx));
    dout[g] = lab;
    dout[GG + g * 2]     = d0 - ls;
    dout[GG + g * 2 + 1] = d1 - ls;
}

// ---------------------------------------------------------------------------
extern "C" void kernel_launch(void* const* d_in, const int* in_sizes, int n_in,
                              void* d_out, int out_size, void* d_ws, size_t ws_size,
                              hipStream_t stream) {
    const float* x   = (const float*)d_in[0];
    const float* ea  = (const float*)d_in[1];
    const int* ei    = (const int*)d_in[2];
    const int* batch = (const int*)d_in[3];
    const float* W0 = (const float*)d_in[5],  *b0 = (const float*)d_in[6];
    const float* We1 = (const float*)d_in[7], *be1 = (const float*)d_in[8];
    const float* We2 = (const float*)d_in[9], *be2 = (const float*)d_in[10];
    const float* Wroot = (const float*)d_in[11], *bconv = (const float*)d_in[12];
    const float* Wih = (const float*)d_in[13], *bih = (const float*)d_in[14];
    const float* Whh = (const float*)d_in[15], *bhh = (const float*)d_in[16];
    const float* W1a = (const float*)d_in[17], *b1a = (const float*)d_in[18];
    const float* W1b = (const float*)d_in[19], *b1b = (const float*)d_in[20];
    const float* W2a = (const float*)d_in[21], *b2a = (const float*)d_in[22];
    const float* W2b = (const float*)d_in[23], *b2b = (const float*)d_in[24];
    float* dout = (float*)d_out;

    char* w = (char*)d_ws;
    u16*   tmat = (u16*)w;    w += (size_t)EE * 32 * 2;   // 16,000,000
    u16*   Bg   = (u16*)w;    w += 33 * 1024 * 2 + 512;   // keep 16B alignment
    float* hf   = (float*)w;  w += (size_t)NN * 32 * 4;
    u16*   cur  = (u16*)w;    w += (size_t)NN * 32 * 2;
    float* agg  = (float*)w;  w += (size_t)NN * 32 * 4;
    float* dinv = (float*)w;  w += 200192;
    int*   degc = (int*)w;    w += 200192;
    float* gsum = (float*)w;  w += (size_t)GG * 32 * 4;
    int*   gcnt = (int*)w;    w += 2048;
    float4* wta_g = (float4*)w; w += 1024 * 16;           // 16 KB
    float2* wtb_g = (float2*)w; w += 1024 * 8;            // 8 KB

    hipMemsetAsync(degc, 0, NN * 4, stream);
    hipMemsetAsync(gcnt, 0, GG * 4, stream);
    hipMemsetAsync(gsum, 0, GG * 32 * 4, stream);

    prep_B<<<132, 256, 0, stream>>>(We2, be2, Bg);
    prep_WT<<<4, 256, 0, stream>>>(Wih, Whh, wta_g, wtb_g);
    prep_edges<<<(EE + 255) / 256, 256, 0, stream>>>(ea, We1, be1, tmat);
    lin0_k<<<(NN + 255) / 256, 256, 0, stream>>>(x, W0, b0, hf, cur);
    hist_k<<<(EE + 255) / 256, 256, 0, stream>>>(ei, batch, degc, gcnt);
    degfin_k<<<(NN + 255) / 256, 256, 0, stream>>>(degc, dinv);

    for (int it = 0; it < 3; it++) {
        hipMemsetAsync(agg, 0, (size_t)NN * 32 * 4, stream);
        msg_k<<<512, 512, 0, stream>>>(cur, tmat, ei, Bg, agg);
        node_update_t<<<(NN + 63) / 64, 256, 0, stream>>>(hf, cur, agg, dinv,
                                                          Wroot, bconv, wta_g, wtb_g, bih, bhh);
    }

    pool_k<<<(NN + 255) / 256, 256, 0, stream>>>(hf, batch, gsum);
    head_k<<<2, 256, 0, stream>>>(gsum, gcnt, W1a, b1a, W1b, b1b, W2a, b2a, W2b, b2b, dout);
}

// Round 6
// 1712.480 us; speedup vs baseline: 1.9329x; 1.9329x over previous
//
#include <hip/hip_runtime.h>

typedef unsigned short u16;
typedef unsigned int u32;

#define NN 50000
#define EE 250000
#define GG 512

typedef __bf16 bf16x8 __attribute__((ext_vector_type(8)));
typedef float  f32x4  __attribute__((ext_vector_type(4)));

__device__ __forceinline__ u16 f2bfu(float f) {
    __bf16 b = (__bf16)f; u16 u; __builtin_memcpy(&u, &b, 2); return u;
}
__device__ __forceinline__ float sigf(float x) { return 1.f / (1.f + expf(-x)); }

// ---------------------------------------------------------------------------
// Build swizzled B (We2 viewed as 1024x32, plus be2 as a 33rd K-step) in
// MFMA fragment order.
// ---------------------------------------------------------------------------
__global__ void prep_B(const float* __restrict__ We2, const float* __restrict__ be2,
                       u16* __restrict__ Bg) {
    int idx = blockIdx.x * blockDim.x + threadIdx.x;
    if (idx >= 33 * 1024) return;
    int kk = idx >> 10, off = idx & 1023;
    int ct = off >> 9, l = (off >> 3) & 63, j = off & 7;
    int q = l >> 4, c = l & 15, o = c + 16 * ct;
    float v;
    if (kk < 32) v = We2[(32 * kk + 8 * q + j) * 32 + o];
    else         v = be2[(8 * q + j) * 32 + o];
    Bg[idx] = f2bfu(v);
}

// ---------------------------------------------------------------------------
// t = relu(edge_attr @ We1 + be1), stored bf16 [E][32]
// ---------------------------------------------------------------------------
__global__ void prep_edges(const float* __restrict__ ea, const float* __restrict__ We1,
                           const float* __restrict__ be1, u16* __restrict__ tmat) {
    int e = blockIdx.x * blockDim.x + threadIdx.x;
    if (e >= EE) return;
    const float4* ep = (const float4*)(ea + (size_t)e * 16);
    float a[16];
#pragma unroll
    for (int i = 0; i < 4; i++) {
        float4 v = ep[i];
        a[4 * i] = v.x; a[4 * i + 1] = v.y; a[4 * i + 2] = v.z; a[4 * i + 3] = v.w;
    }
    u32 outw[16];
#pragma unroll
    for (int p = 0; p < 16; p++) {
        float acc0 = be1[2 * p], acc1 = be1[2 * p + 1];
#pragma unroll
        for (int k = 0; k < 16; k++) {
            acc0 += a[k] * We1[k * 32 + 2 * p];
            acc1 += a[k] * We1[k * 32 + 2 * p + 1];
        }
        acc0 = fmaxf(acc0, 0.f); acc1 = fmaxf(acc1, 0.f);
        outw[p] = (u32)f2bfu(acc0) | ((u32)f2bfu(acc1) << 16);
    }
    uint4* op = (uint4*)(tmat + (size_t)e * 32);
#pragma unroll
    for (int i = 0; i < 4; i++)
        op[i] = make_uint4(outw[4 * i], outw[4 * i + 1], outw[4 * i + 2], outw[4 * i + 3]);
}

// ---------------------------------------------------------------------------
// h = relu(x @ W0 + b0); write f32 state + bf16 mirror
// ---------------------------------------------------------------------------
__global__ void lin0_k(const float* __restrict__ x, const float* __restrict__ W0,
                       const float* __restrict__ b0, float* __restrict__ hf,
                       u16* __restrict__ cur) {
    int n = blockIdx.x * blockDim.x + threadIdx.x;
    if (n >= NN) return;
    const float4* xp = (const float4*)(x + (size_t)n * 32);
    float a[32];
#pragma unroll
    for (int i = 0; i < 8; i++) {
        float4 v = xp[i];
        a[4 * i] = v.x; a[4 * i + 1] = v.y; a[4 * i + 2] = v.z; a[4 * i + 3] = v.w;
    }
    float o[32];
#pragma unroll 4
    for (int c = 0; c < 32; c++) {
        float acc = b0[c];
#pragma unroll
        for (int k = 0; k < 32; k++) acc += a[k] * W0[k * 32 + c];
        o[c] = fmaxf(acc, 0.f);
    }
    float4* hp = (float4*)(hf + (size_t)n * 32);
#pragma unroll
    for (int i = 0; i < 8; i++) hp[i] = make_float4(o[4 * i], o[4 * i + 1], o[4 * i + 2], o[4 * i + 3]);
    uint4* cp = (uint4*)(cur + (size_t)n * 32);
#pragma unroll
    for (int i = 0; i < 4; i++) {
        u32 p0 = (u32)f2bfu(o[8 * i + 0]) | ((u32)f2bfu(o[8 * i + 1]) << 16);
        u32 p1 = (u32)f2bfu(o[8 * i + 2]) | ((u32)f2bfu(o[8 * i + 3]) << 16);
        u32 p2 = (u32)f2bfu(o[8 * i + 4]) | ((u32)f2bfu(o[8 * i + 5]) << 16);
        u32 p3 = (u32)f2bfu(o[8 * i + 6]) | ((u32)f2bfu(o[8 * i + 7]) << 16);
        cp[i] = make_uint4(p0, p1, p2, p3);
    }
}

// ---------------------------------------------------------------------------
// histograms
// ---------------------------------------------------------------------------
__global__ void hist_k(const int* __restrict__ ei, const int* __restrict__ batch,
                       int* __restrict__ degc, int* __restrict__ gcnt) {
    int i = blockIdx.x * blockDim.x + threadIdx.x;
    if (i < EE) atomicAdd(degc + ei[EE + i], 1);
    if (i < NN) atomicAdd(gcnt + batch[i], 1);
}

__global__ void degfin_k(const int* __restrict__ degc, float* __restrict__ dinv) {
    int n = blockIdx.x * blockDim.x + threadIdx.x;
    if (n >= NN) return;
    int c = degc[n];
    dinv[n] = 1.f / (float)(c > 0 ? c : 1);
}

// ---------------------------------------------------------------------------
// Message kernel (unchanged)
// ---------------------------------------------------------------------------
__global__ __launch_bounds__(512) void msg_k(const u16* __restrict__ cur,
                                             const u16* __restrict__ tmat,
                                             const int* __restrict__ ei,
                                             const u16* __restrict__ Bg,
                                             float* __restrict__ agg) {
    __shared__ uint4 Bl[4096];
    const uint4* Bgv = (const uint4*)Bg;
    for (int i = threadIdx.x; i < 4096; i += 512) Bl[i] = Bgv[i];
    __syncthreads();
    const u16* Bl16 = (const u16*)Bl;

    int l = threadIdx.x & 63;
    int q = l >> 4, r = l & 15;
    int wid = (blockIdx.x * blockDim.x + threadIdx.x) >> 6;
    int nw  = (gridDim.x * blockDim.x) >> 6;

    for (int tile = wid; tile < EE / 16; tile += nw) {
        int eb = tile * 16;
        int srow = ei[eb + r];
        bf16x8 sv = *reinterpret_cast<const bf16x8*>(cur + (size_t)srow * 32 + q * 8);
        float sf[8];
#pragma unroll
        for (int j = 0; j < 8; j++) sf[j] = (float)sv[j];
        const uint4* tp = reinterpret_cast<const uint4*>(tmat + (size_t)(eb + r) * 32);
        f32x4 acc0 = {0.f, 0.f, 0.f, 0.f}, acc1 = {0.f, 0.f, 0.f, 0.f};
#pragma unroll
        for (int kq = 0; kq < 4; kq++) {
            uint4 tw4 = tp[kq];
            u32 tws[4] = {tw4.x, tw4.y, tw4.z, tw4.w};
#pragma unroll
            for (int du = 0; du < 4; du++) {
                u32 w = tws[du];
#pragma unroll
                for (int hl = 0; hl < 2; hl++) {
                    int kk = kq * 8 + du * 2 + hl;
                    float tf = __uint_as_float(hl ? (w & 0xffff0000u) : (w << 16));
                    bf16x8 av;
#pragma unroll
                    for (int j = 0; j < 8; j++) av[j] = (__bf16)(tf * sf[j]);
                    bf16x8 b0 = *reinterpret_cast<const bf16x8*>(Bl16 + kk * 1024 + l * 8);
                    bf16x8 b1 = *reinterpret_cast<const bf16x8*>(Bl16 + kk * 1024 + 512 + l * 8);
                    acc0 = __builtin_amdgcn_mfma_f32_16x16x32_bf16(av, b0, acc0, 0, 0, 0);
                    acc1 = __builtin_amdgcn_mfma_f32_16x16x32_bf16(av, b1, acc1, 0, 0, 0);
                }
            }
        }
        {
            bf16x8 b0 = *reinterpret_cast<const bf16x8*>(Bg + 32 * 1024 + l * 8);
            bf16x8 b1 = *reinterpret_cast<const bf16x8*>(Bg + 32 * 1024 + 512 + l * 8);
            acc0 = __builtin_amdgcn_mfma_f32_16x16x32_bf16(sv, b0, acc0, 0, 0, 0);
            acc1 = __builtin_amdgcn_mfma_f32_16x16x32_bf16(sv, b1, acc1, 0, 0, 0);
        }
#pragma unroll
        for (int j = 0; j < 4; j++) {
            int d = ei[EE + eb + 4 * q + j];
            atomicAdd(agg + (size_t)d * 32 + r,      acc0[j]);
            atomicAdd(agg + (size_t)d * 32 + 16 + r, acc1[j]);
        }
    }
}

// ---------------------------------------------------------------------------
// node_update_v3: lane = node (64 nodes/block), wave = 8-column slice.
// Weights via wave-uniform s_loads (no LDS staging, no per-thread streaming).
// h/m in registers (static indexing only); m exchanged via LDS; coalesced
// writeout through LDS. Accumulators capped at 24 (two 4-col halves).
// ---------------------------------------------------------------------------
__global__ __launch_bounds__(256) void node_update_v3(
        float* __restrict__ hf, u16* __restrict__ cur,
        const float* __restrict__ agg, const float* __restrict__ dinv,
        const float* __restrict__ Wroot, const float* __restrict__ bconv,
        const float* __restrict__ Wih, const float* __restrict__ bih,
        const float* __restrict__ Whh, const float* __restrict__ bhh) {
    __shared__ float xch[4224];          // h_l[32][66] | m_l[32][66]; reused as out[64][36]
    float* h_l = xch;
    float* m_l = xch + 2112;

    const int t = threadIdx.x;
    const int w = t >> 6;                // wave 0..3
    const int lane = t & 63;
    const int nb = blockIdx.x * 64;
    const int n = nb + lane;
    const int nc = (n < NN) ? n : (NN - 1);

    // ---- load h into regs (coalesced) + LDS copy (for runtime-j epilogue) ----
    float h_[32];
    {
        const float4* hp = (const float4*)(hf + (size_t)nc * 32);
#pragma unroll
        for (int i = 0; i < 8; i++) {
            float4 v = hp[i];
            h_[4 * i] = v.x; h_[4 * i + 1] = v.y; h_[4 * i + 2] = v.z; h_[4 * i + 3] = v.w;
        }
    }
#pragma unroll
    for (int k = 0; k < 32; k++) h_l[k * 66 + lane] = h_[k];

    // ---- phase B: m = relu(bconv + agg*dinv + h @ Wroot), wave's 8 cols ----
    const int c0 = w * 8;
    {
        float acc[8];
        const float di = dinv[nc];
        const float4* ap = (const float4*)(agg + (size_t)nc * 32 + c0);
        float4 a0 = ap[0], a1 = ap[1];
        acc[0] = bconv[c0 + 0] + a0.x * di; acc[1] = bconv[c0 + 1] + a0.y * di;
        acc[2] = bconv[c0 + 2] + a0.z * di; acc[3] = bconv[c0 + 3] + a0.w * di;
        acc[4] = bconv[c0 + 4] + a1.x * di; acc[5] = bconv[c0 + 5] + a1.y * di;
        acc[6] = bconv[c0 + 6] + a1.z * di; acc[7] = bconv[c0 + 7] + a1.w * di;
#pragma unroll
        for (int k = 0; k < 32; k++) {
            const float* wr = Wroot + k * 32 + c0;   // wave-uniform -> s_load
#pragma unroll
            for (int j = 0; j < 8; j++) acc[j] = fmaf(h_[k], wr[j], acc[j]);
        }
#pragma unroll
        for (int j = 0; j < 8; j++) m_l[(c0 + j) * 66 + lane] = fmaxf(acc[j], 0.f);
    }
    __syncthreads();

    float m_[32];
#pragma unroll
    for (int k = 0; k < 32; k++) m_[k] = m_l[k * 66 + lane];

    // ---- phase C: gates for wave's 8 j's, two halves of 4 (24 acc live) ----
    float outv[8];
#pragma unroll
    for (int half = 0; half < 2; half++) {
        const int j0 = w * 8 + half * 4;
        float air[4], aiz[4], ain[4], ahr[4], ahz[4], ahn[4];
#pragma unroll
        for (int jj = 0; jj < 4; jj++) {
            air[jj] = 0.f; aiz[jj] = 0.f; ain[jj] = 0.f;
            ahr[jj] = 0.f; ahz[jj] = 0.f; ahn[jj] = 0.f;
        }
#pragma unroll
        for (int k = 0; k < 32; k++) {
#pragma unroll
            for (int jj = 0; jj < 4; jj++) {
                const int j = j0 + jj;               // wave-uniform rows -> s_load
                air[jj] = fmaf(m_[k], Wih[j * 32 + k],        air[jj]);
                aiz[jj] = fmaf(m_[k], Wih[(32 + j) * 32 + k], aiz[jj]);
                ain[jj] = fmaf(m_[k], Wih[(64 + j) * 32 + k], ain[jj]);
                ahr[jj] = fmaf(h_[k], Whh[j * 32 + k],        ahr[jj]);
                ahz[jj] = fmaf(h_[k], Whh[(32 + j) * 32 + k], ahz[jj]);
                ahn[jj] = fmaf(h_[k], Whh[(64 + j) * 32 + k], ahn[jj]);
            }
        }
#pragma unroll
        for (int jj = 0; jj < 4; jj++) {
            const int j = j0 + jj;
            float r = sigf(air[jj] + ahr[jj] + bih[j] + bhh[j]);
            float z = sigf(aiz[jj] + ahz[jj] + bih[32 + j] + bhh[32 + j]);
            float g = tanhf(ain[jj] + bih[64 + j] + r * (ahn[jj] + bhh[64 + j]));
            float ho = h_l[j * 66 + lane];           // runtime j -> LDS, not regs
            outv[half * 4 + jj] = (1.f - z) * g + z * ho;
        }
    }
    __syncthreads();                                  // all h_l/m_l reads done

    // out[node][j], row stride 36 (16B-aligned rows for float4 readback)
#pragma unroll
    for (int u2 = 0; u2 < 8; u2++) xch[lane * 36 + w * 8 + u2] = outv[u2];
    __syncthreads();

    // ---- coalesced writeout: thread -> node t>>2, col-quarter (t&3)*8 ----
    {
        const int nl = t >> 2, q = (t & 3) * 8;
        const int ng = nb + nl;
        if (ng < NN) {
            float4 v0 = *(const float4*)&xch[nl * 36 + q];
            float4 v1 = *(const float4*)&xch[nl * 36 + q + 4];
            *(float4*)(hf + (size_t)ng * 32 + q)     = v0;
            *(float4*)(hf + (size_t)ng * 32 + q + 4) = v1;
            u32 p0 = (u32)f2bfu(v0.x) | ((u32)f2bfu(v0.y) << 16);
            u32 p1 = (u32)f2bfu(v0.z) | ((u32)f2bfu(v0.w) << 16);
            u32 p2 = (u32)f2bfu(v1.x) | ((u32)f2bfu(v1.y) << 16);
            u32 p3 = (u32)f2bfu(v1.z) | ((u32)f2bfu(v1.w) << 16);
            *(uint4*)(cur + (size_t)ng * 32 + q) = make_uint4(p0, p1, p2, p3);
        }
    }
}

__global__ void pool_k(const float* __restrict__ hf, const int* __restrict__ batch,
                       float* __restrict__ gsum) {
    int n = blockIdx.x * blockDim.x + threadIdx.x;
    if (n >= NN) return;
    int g = batch[n];
#pragma unroll 8
    for (int o = 0; o < 32; o++) atomicAdd(gsum + g * 32 + o, hf[(size_t)n * 32 + o]);
}

// ---------------------------------------------------------------------------
// Heads: OUTPUT IS FLOAT32
// ---------------------------------------------------------------------------
__global__ void head_k(const float* __restrict__ gsum, const int* __restrict__ gcnt,
                       const float* __restrict__ W1a, const float* __restrict__ b1a,
                       const float* __restrict__ W1b, const float* __restrict__ b1b,
                       const float* __restrict__ W2a, const float* __restrict__ b2a,
                       const float* __restrict__ W2b, const float* __restrict__ b2b,
                       float* __restrict__ dout) {
    int g = blockIdx.x * blockDim.x + threadIdx.x;
    if (g >= GG) return;
    int c0 = gcnt[g];
    float rc = 1.f / (float)(c0 > 0 ? c0 : 1);
    float p[32];
#pragma unroll
    for (int i = 0; i < 32; i++) p[i] = gsum[g * 32 + i] * rc;
    float lab = b1b[0];
#pragma unroll 4
    for (int c = 0; c < 32; c++) {
        float acc = b1a[c];
#pragma unroll
        for (int k = 0; k < 32; k++) acc += p[k] * W1a[k * 32 + c];
        lab += fmaxf(acc, 0.f) * W1b[c];
    }
    float d0 = b2b[0], d1 = b2b[1];
#pragma unroll 4
    for (int c = 0; c < 32; c++) {
        float acc = b2a[c];
#pragma unroll
        for (int k = 0; k < 32; k++) acc += p[k] * W2a[k * 32 + c];
        float t = fmaxf(acc, 0.f);
        d0 += t * W2b[c * 2];
        d1 += t * W2b[c * 2 + 1];
    }
    float mx = fmaxf(d0, d1);
    float ls = mx + logf(expf(d0 - mx) + expf(d1 - mx));
    dout[g] = lab;
    dout[GG + g * 2]     = d0 - ls;
    dout[GG + g * 2 + 1] = d1 - ls;
}

// ---------------------------------------------------------------------------
extern "C" void kernel_launch(void* const* d_in, const int* in_sizes, int n_in,
                              void* d_out, int out_size, void* d_ws, size_t ws_size,
                              hipStream_t stream) {
    const float* x   = (const float*)d_in[0];
    const float* ea  = (const float*)d_in[1];
    const int* ei    = (const int*)d_in[2];
    const int* batch = (const int*)d_in[3];
    const float* W0 = (const float*)d_in[5],  *b0 = (const float*)d_in[6];
    const float* We1 = (const float*)d_in[7], *be1 = (const float*)d_in[8];
    const float* We2 = (const float*)d_in[9], *be2 = (const float*)d_in[10];
    const float* Wroot = (const float*)d_in[11], *bconv = (const float*)d_in[12];
    const float* Wih = (const float*)d_in[13], *bih = (const float*)d_in[14];
    const float* Whh = (const float*)d_in[15], *bhh = (const float*)d_in[16];
    const float* W1a = (const float*)d_in[17], *b1a = (const float*)d_in[18];
    const float* W1b = (const float*)d_in[19], *b1b = (const float*)d_in[20];
    const float* W2a = (const float*)d_in[21], *b2a = (const float*)d_in[22];
    const float* W2b = (const float*)d_in[23], *b2b = (const float*)d_in[24];
    float* dout = (float*)d_out;

    char* w = (char*)d_ws;
    u16*   tmat = (u16*)w;    w += (size_t)EE * 32 * 2;   // 16,000,000
    u16*   Bg   = (u16*)w;    w += 33 * 1024 * 2 + 512;
    float* hf   = (float*)w;  w += (size_t)NN * 32 * 4;
    u16*   cur  = (u16*)w;    w += (size_t)NN * 32 * 2;
    float* agg  = (float*)w;  w += (size_t)NN * 32 * 4;
    float* dinv = (float*)w;  w += 200192;
    int*   degc = (int*)w;    w += 200192;
    float* gsum = (float*)w;  w += (size_t)GG * 32 * 4;
    int*   gcnt = (int*)w;    w += 2048;

    hipMemsetAsync(degc, 0, NN * 4, stream);
    hipMemsetAsync(gcnt, 0, GG * 4, stream);
    hipMemsetAsync(gsum, 0, GG * 32 * 4, stream);

    prep_B<<<132, 256, 0, stream>>>(We2, be2, Bg);
    prep_edges<<<(EE + 255) / 256, 256, 0, stream>>>(ea, We1, be1, tmat);
    lin0_k<<<(NN + 255) / 256, 256, 0, stream>>>(x, W0, b0, hf, cur);
    hist_k<<<(EE + 255) / 256, 256, 0, stream>>>(ei, batch, degc, gcnt);
    degfin_k<<<(NN + 255) / 256, 256, 0, stream>>>(degc, dinv);

    for (int it = 0; it < 3; it++) {
        hipMemsetAsync(agg, 0, (size_t)NN * 32 * 4, stream);
        msg_k<<<512, 512, 0, stream>>>(cur, tmat, ei, Bg, agg);
        node_update_v3<<<(NN + 63) / 64, 256, 0, stream>>>(hf, cur, agg, dinv,
                                                           Wroot, bconv, Wih, bih, Whh, bhh);
    }

    pool_k<<<(NN + 255) / 256, 256, 0, stream>>>(hf, batch, gsum);
    head_k<<<2, 256, 0, stream>>>(gsum, gcnt, W1a, b1a, W1b, b1b, W2a, b2a, W2b, b2b, dout);
}

// Round 8
// 713.591 us; speedup vs baseline: 4.6386x; 2.3998x over previous
//
#include <hip/hip_runtime.h>

typedef unsigned short u16;
typedef unsigned int u32;

#define NN 50000
#define EE 250000
#define GG 512

typedef __bf16 bf16x8 __attribute__((ext_vector_type(8)));
typedef float  f32x4  __attribute__((ext_vector_type(4)));

__device__ __forceinline__ u16 f2bfu(float f) {
    __bf16 b = (__bf16)f; u16 u; __builtin_memcpy(&u, &b, 2); return u;
}
__device__ __forceinline__ float sigf(float x) { return 1.f / (1.f + expf(-x)); }

// ---------------------------------------------------------------------------
// Build swizzled B (We2 viewed as 1024x32, plus be2 as a 33rd K-step) in
// MFMA fragment order.
// ---------------------------------------------------------------------------
__global__ void prep_B(const float* __restrict__ We2, const float* __restrict__ be2,
                       u16* __restrict__ Bg) {
    int idx = blockIdx.x * blockDim.x + threadIdx.x;
    if (idx >= 33 * 1024) return;
    int kk = idx >> 10, off = idx & 1023;
    int ct = off >> 9, l = (off >> 3) & 63, j = off & 7;
    int q = l >> 4, c = l & 15, o = c + 16 * ct;
    float v;
    if (kk < 32) v = We2[(32 * kk + 8 * q + j) * 32 + o];
    else         v = be2[(8 * q + j) * 32 + o];
    Bg[idx] = f2bfu(v);
}

// ---------------------------------------------------------------------------
// Pack GRU gate weights: wta[k*32+j] = {Wih_r, Wih_z, Wih_n, Whh_r}[j][k]
//                        wtb[k*32+j] = {Whh_z, Whh_n}[j][k]
// ---------------------------------------------------------------------------
__global__ void prep_WT(const float* __restrict__ Wih, const float* __restrict__ Whh,
                        float4* __restrict__ wta, float2* __restrict__ wtb) {
    int t = blockIdx.x * blockDim.x + threadIdx.x;
    if (t >= 1024) return;
    int k = t >> 5, j = t & 31;
    wta[t] = make_float4(Wih[j * 32 + k], Wih[(32 + j) * 32 + k],
                         Wih[(64 + j) * 32 + k], Whh[j * 32 + k]);
    wtb[t] = make_float2(Whh[(32 + j) * 32 + k], Whh[(64 + j) * 32 + k]);
}

// ---------------------------------------------------------------------------
// t = relu(edge_attr @ We1 + be1), stored bf16 [E][32]
// ---------------------------------------------------------------------------
__global__ void prep_edges(const float* __restrict__ ea, const float* __restrict__ We1,
                           const float* __restrict__ be1, u16* __restrict__ tmat) {
    int e = blockIdx.x * blockDim.x + threadIdx.x;
    if (e >= EE) return;
    const float4* ep = (const float4*)(ea + (size_t)e * 16);
    float a[16];
#pragma unroll
    for (int i = 0; i < 4; i++) {
        float4 v = ep[i];
        a[4 * i] = v.x; a[4 * i + 1] = v.y; a[4 * i + 2] = v.z; a[4 * i + 3] = v.w;
    }
    u32 outw[16];
#pragma unroll
    for (int p = 0; p < 16; p++) {
        float acc0 = be1[2 * p], acc1 = be1[2 * p + 1];
#pragma unroll
        for (int k = 0; k < 16; k++) {
            acc0 += a[k] * We1[k * 32 + 2 * p];
            acc1 += a[k] * We1[k * 32 + 2 * p + 1];
        }
        acc0 = fmaxf(acc0, 0.f); acc1 = fmaxf(acc1, 0.f);
        outw[p] = (u32)f2bfu(acc0) | ((u32)f2bfu(acc1) << 16);
    }
    uint4* op = (uint4*)(tmat + (size_t)e * 32);
#pragma unroll
    for (int i = 0; i < 4; i++)
        op[i] = make_uint4(outw[4 * i], outw[4 * i + 1], outw[4 * i + 2], outw[4 * i + 3]);
}

// ---------------------------------------------------------------------------
// h = relu(x @ W0 + b0); write f32 state + bf16 mirror
// ---------------------------------------------------------------------------
__global__ void lin0_k(const float* __restrict__ x, const float* __restrict__ W0,
                       const float* __restrict__ b0, float* __restrict__ hf,
                       u16* __restrict__ cur) {
    int n = blockIdx.x * blockDim.x + threadIdx.x;
    if (n >= NN) return;
    const float4* xp = (const float4*)(x + (size_t)n * 32);
    float a[32];
#pragma unroll
    for (int i = 0; i < 8; i++) {
        float4 v = xp[i];
        a[4 * i] = v.x; a[4 * i + 1] = v.y; a[4 * i + 2] = v.z; a[4 * i + 3] = v.w;
    }
    float o[32];
#pragma unroll 4
    for (int c = 0; c < 32; c++) {
        float acc = b0[c];
#pragma unroll
        for (int k = 0; k < 32; k++) acc += a[k] * W0[k * 32 + c];
        o[c] = fmaxf(acc, 0.f);
    }
    float4* hp = (float4*)(hf + (size_t)n * 32);
#pragma unroll
    for (int i = 0; i < 8; i++) hp[i] = make_float4(o[4 * i], o[4 * i + 1], o[4 * i + 2], o[4 * i + 3]);
    uint4* cp = (uint4*)(cur + (size_t)n * 32);
#pragma unroll
    for (int i = 0; i < 4; i++) {
        u32 p0 = (u32)f2bfu(o[8 * i + 0]) | ((u32)f2bfu(o[8 * i + 1]) << 16);
        u32 p1 = (u32)f2bfu(o[8 * i + 2]) | ((u32)f2bfu(o[8 * i + 3]) << 16);
        u32 p2 = (u32)f2bfu(o[8 * i + 4]) | ((u32)f2bfu(o[8 * i + 5]) << 16);
        u32 p3 = (u32)f2bfu(o[8 * i + 6]) | ((u32)f2bfu(o[8 * i + 7]) << 16);
        cp[i] = make_uint4(p0, p1, p2, p3);
    }
}

// ---------------------------------------------------------------------------
// histograms
// ---------------------------------------------------------------------------
__global__ void hist_k(const int* __restrict__ ei, const int* __restrict__ batch,
                       int* __restrict__ degc, int* __restrict__ gcnt) {
    int i = blockIdx.x * blockDim.x + threadIdx.x;
    if (i < EE) atomicAdd(degc + ei[EE + i], 1);
    if (i < NN) atomicAdd(gcnt + batch[i], 1);
}

__global__ void degfin_k(const int* __restrict__ degc, float* __restrict__ dinv) {
    int n = blockIdx.x * blockDim.x + threadIdx.x;
    if (n >= NN) return;
    int c = degc[n];
    dinv[n] = 1.f / (float)(c > 0 ? c : 1);
}

// ---------------------------------------------------------------------------
// Message kernel (unchanged)
// ---------------------------------------------------------------------------
__global__ __launch_bounds__(512) void msg_k(const u16* __restrict__ cur,
                                             const u16* __restrict__ tmat,
                                             const int* __restrict__ ei,
                                             const u16* __restrict__ Bg,
                                             float* __restrict__ agg) {
    __shared__ uint4 Bl[4096];
    const uint4* Bgv = (const uint4*)Bg;
    for (int i = threadIdx.x; i < 4096; i += 512) Bl[i] = Bgv[i];
    __syncthreads();
    const u16* Bl16 = (const u16*)Bl;

    int l = threadIdx.x & 63;
    int q = l >> 4, r = l & 15;
    int wid = (blockIdx.x * blockDim.x + threadIdx.x) >> 6;
    int nw  = (gridDim.x * blockDim.x) >> 6;

    for (int tile = wid; tile < EE / 16; tile += nw) {
        int eb = tile * 16;
        int srow = ei[eb + r];
        bf16x8 sv = *reinterpret_cast<const bf16x8*>(cur + (size_t)srow * 32 + q * 8);
        float sf[8];
#pragma unroll
        for (int j = 0; j < 8; j++) sf[j] = (float)sv[j];
        const uint4* tp = reinterpret_cast<const uint4*>(tmat + (size_t)(eb + r) * 32);
        f32x4 acc0 = {0.f, 0.f, 0.f, 0.f}, acc1 = {0.f, 0.f, 0.f, 0.f};
#pragma unroll
        for (int kq = 0; kq < 4; kq++) {
            uint4 tw4 = tp[kq];
            u32 tws[4] = {tw4.x, tw4.y, tw4.z, tw4.w};
#pragma unroll
            for (int du = 0; du < 4; du++) {
                u32 w = tws[du];
#pragma unroll
                for (int hl = 0; hl < 2; hl++) {
                    int kk = kq * 8 + du * 2 + hl;
                    float tf = __uint_as_float(hl ? (w & 0xffff0000u) : (w << 16));
                    bf16x8 av;
#pragma unroll
                    for (int j = 0; j < 8; j++) av[j] = (__bf16)(tf * sf[j]);
                    bf16x8 b0 = *reinterpret_cast<const bf16x8*>(Bl16 + kk * 1024 + l * 8);
                    bf16x8 b1 = *reinterpret_cast<const bf16x8*>(Bl16 + kk * 1024 + 512 + l * 8);
                    acc0 = __builtin_amdgcn_mfma_f32_16x16x32_bf16(av, b0, acc0, 0, 0, 0);
                    acc1 = __builtin_amdgcn_mfma_f32_16x16x32_bf16(av, b1, acc1, 0, 0, 0);
                }
            }
        }
        {
            bf16x8 b0 = *reinterpret_cast<const bf16x8*>(Bg + 32 * 1024 + l * 8);
            bf16x8 b1 = *reinterpret_cast<const bf16x8*>(Bg + 32 * 1024 + 512 + l * 8);
            acc0 = __builtin_amdgcn_mfma_f32_16x16x32_bf16(sv, b0, acc0, 0, 0, 0);
            acc1 = __builtin_amdgcn_mfma_f32_16x16x32_bf16(sv, b1, acc1, 0, 0, 0);
        }
#pragma unroll
        for (int j = 0; j < 4; j++) {
            int d = ei[EE + eb + 4 * q + j];
            atomicAdd(agg + (size_t)d * 32 + r,      acc0[j]);
            atomicAdd(agg + (size_t)d * 32 + 16 + r, acc1[j]);
        }
    }
}

// ---------------------------------------------------------------------------
// node_update_v4: spill-proof. Block = 512 thr = 64 nodes x 8 waves.
// lane = node; wave w owns 4 output columns. NO register arrays for h/m —
// they live in LDS (stride 66, 2-way=free). Weights staged in LDS, read as
// same-address broadcasts. Only 12 accumulators live. k-loops partial-unroll
// with runtime k (indexes LDS only).
// ---------------------------------------------------------------------------
__global__ __launch_bounds__(512) void node_update_v4(
        float* __restrict__ hf, u16* __restrict__ cur,
        const float* __restrict__ agg, const float* __restrict__ dinv,
        const float* __restrict__ Wroot, const float* __restrict__ bconv,
        const float4* __restrict__ wta_g, const float2* __restrict__ wtb_g,
        const float* __restrict__ bih, const float* __restrict__ bhh) {
    __shared__ float  wroot_l[1024];      //  4 KB
    __shared__ float4 wta_l[1024];        // 16 KB
    __shared__ float2 wtb_l[1024];        //  8 KB
    __shared__ float  h_l[32 * 66];       //  8.25 KB  h[k][node]
    __shared__ float  m_l[32 * 66];       //  8.25 KB  m[c][node]; reused as out
    __shared__ float  bias_l[192];

    const int t = threadIdx.x;
    const int w = t >> 6;                 // wave 0..7
    const int lane = t & 63;              // node within block
    const int nb = blockIdx.x * 64;
    const int n = nb + lane;
    const int nc = (n < NN) ? n : (NN - 1);

    // ---- stage weights (coalesced) ----
    if (t < 256) ((float4*)wroot_l)[t] = ((const float4*)Wroot)[t];
    wta_l[t] = wta_g[t]; wta_l[t + 512] = wta_g[t + 512];
    ((float4*)wtb_l)[t] = ((const float4*)wtb_g)[t];
    if (t < 192) bias_l[t] = (t < 96) ? bih[t] : bhh[t - 96];

    // ---- stage h tile: thread t -> node t>>3, float4 chunk t&7 (coalesced) ----
    {
        const int nl = t >> 3, ch = t & 7;
        const int ng = nb + nl;
        const int ngc = (ng < NN) ? ng : (NN - 1);
        float4 v = *(const float4*)(hf + (size_t)ngc * 32 + ch * 4);
        h_l[(ch * 4 + 0) * 66 + nl] = v.x;
        h_l[(ch * 4 + 1) * 66 + nl] = v.y;
        h_l[(ch * 4 + 2) * 66 + nl] = v.z;
        h_l[(ch * 4 + 3) * 66 + nl] = v.w;
    }
    __syncthreads();

    // ---- Phase B: m[c0..c0+3] = relu(bconv + agg*dinv + h@Wroot) ----
    const int c0 = w * 4;
    {
        const float di = dinv[nc];
        float4 ag = *(const float4*)(agg + (size_t)nc * 32 + c0);
        float a0 = bconv[c0 + 0] + ag.x * di;
        float a1 = bconv[c0 + 1] + ag.y * di;
        float a2 = bconv[c0 + 2] + ag.z * di;
        float a3 = bconv[c0 + 3] + ag.w * di;
#pragma unroll 4
        for (int k = 0; k < 32; k++) {
            float hk = h_l[k * 66 + lane];
            float4 wr = *(const float4*)&wroot_l[k * 32 + c0];   // broadcast
            a0 = fmaf(hk, wr.x, a0); a1 = fmaf(hk, wr.y, a1);
            a2 = fmaf(hk, wr.z, a2); a3 = fmaf(hk, wr.w, a3);
        }
        m_l[(c0 + 0) * 66 + lane] = fmaxf(a0, 0.f);
        m_l[(c0 + 1) * 66 + lane] = fmaxf(a1, 0.f);
        m_l[(c0 + 2) * 66 + lane] = fmaxf(a2, 0.f);
        m_l[(c0 + 3) * 66 + lane] = fmaxf(a3, 0.f);
    }
    __syncthreads();

    // ---- Phase C: gates for 4 j's in 2 halves of 2 (12 acc live) ----
    float outv[4];
#pragma unroll
    for (int half = 0; half < 2; half++) {
        const int j0 = c0 + half * 2;
        float air0 = 0.f, aiz0 = 0.f, ain0 = 0.f, ahr0 = 0.f, ahz0 = 0.f, ahn0 = 0.f;
        float air1 = 0.f, aiz1 = 0.f, ain1 = 0.f, ahr1 = 0.f, ahz1 = 0.f, ahn1 = 0.f;
#pragma unroll 4
        for (int k = 0; k < 32; k++) {
            float mk = m_l[k * 66 + lane];
            float hk = h_l[k * 66 + lane];
            float4 wa0 = wta_l[k * 32 + j0];                     // broadcast
            float2 wb0 = wtb_l[k * 32 + j0];
            float4 wa1 = wta_l[k * 32 + j0 + 1];
            float2 wb1 = wtb_l[k * 32 + j0 + 1];
            air0 = fmaf(mk, wa0.x, air0); aiz0 = fmaf(mk, wa0.y, aiz0);
            ain0 = fmaf(mk, wa0.z, ain0); ahr0 = fmaf(hk, wa0.w, ahr0);
            ahz0 = fmaf(hk, wb0.x, ahz0); ahn0 = fmaf(hk, wb0.y, ahn0);
            air1 = fmaf(mk, wa1.x, air1); aiz1 = fmaf(mk, wa1.y, aiz1);
            ain1 = fmaf(mk, wa1.z, ain1); ahr1 = fmaf(hk, wa1.w, ahr1);
            ahz1 = fmaf(hk, wb1.x, ahz1); ahn1 = fmaf(hk, wb1.y, ahn1);
        }
#pragma unroll
        for (int jj = 0; jj < 2; jj++) {
            const int j = j0 + jj;
            float air = jj ? air1 : air0, aiz = jj ? aiz1 : aiz0, ain = jj ? ain1 : ain0;
            float ahr = jj ? ahr1 : ahr0, ahz = jj ? ahz1 : ahz0, ahn = jj ? ahn1 : ahn0;
            float r = sigf(air + ahr + bias_l[j] + bias_l[96 + j]);
            float z = sigf(aiz + ahz + bias_l[32 + j] + bias_l[128 + j]);
            float g = tanhf(ain + bias_l[64 + j] + r * (ahn + bias_l[160 + j]));
            float ho = h_l[j * 66 + lane];
            outv[half * 2 + jj] = (1.f - z) * g + z * ho;
        }
    }
    __syncthreads();                       // all m_l reads complete

    // ---- out -> m_l (reuse), then coalesced writeout ----
#pragma unroll
    for (int i = 0; i < 4; i++) m_l[(c0 + i) * 66 + lane] = outv[i];
    __syncthreads();

    {
        const int nl = t >> 3, q = (t & 7) * 4;
        const int ng = nb + nl;
        if (ng < NN) {
            float4 v = make_float4(m_l[(q + 0) * 66 + nl], m_l[(q + 1) * 66 + nl],
                                   m_l[(q + 2) * 66 + nl], m_l[(q + 3) * 66 + nl]);
            *(float4*)(hf + (size_t)ng * 32 + q) = v;
            u32 p0 = (u32)f2bfu(v.x) | ((u32)f2bfu(v.y) << 16);
            u32 p1 = (u32)f2bfu(v.z) | ((u32)f2bfu(v.w) << 16);
            *(uint2*)(cur + (size_t)ng * 32 + q) = make_uint2(p0, p1);
        }
    }
}

__global__ void pool_k(const float* __restrict__ hf, const int* __restrict__ batch,
                       float* __restrict__ gsum) {
    int n = blockIdx.x * blockDim.x + threadIdx.x;
    if (n >= NN) return;
    int g = batch[n];
#pragma unroll 8
    for (int o = 0; o < 32; o++) atomicAdd(gsum + g * 32 + o, hf[(size_t)n * 32 + o]);
}

// ---------------------------------------------------------------------------
// Heads: OUTPUT IS FLOAT32
// ---------------------------------------------------------------------------
__global__ void head_k(const float* __restrict__ gsum, const int* __restrict__ gcnt,
                       const float* __restrict__ W1a, const float* __restrict__ b1a,
                       const float* __restrict__ W1b, const float* __restrict__ b1b,
                       const float* __restrict__ W2a, const float* __restrict__ b2a,
                       const float* __restrict__ W2b, const float* __restrict__ b2b,
                       float* __restrict__ dout) {
    int g = blockIdx.x * blockDim.x + threadIdx.x;
    if (g >= GG) return;
    int c0 = gcnt[g];
    float rc = 1.f / (float)(c0 > 0 ? c0 : 1);
    float p[32];
#pragma unroll
    for (int i = 0; i < 32; i++) p[i] = gsum[g * 32 + i] * rc;
    float lab = b1b[0];
#pragma unroll 4
    for (int c = 0; c < 32; c++) {
        float acc = b1a[c];
#pragma unroll
        for (int k = 0; k < 32; k++) acc += p[k] * W1a[k * 32 + c];
        lab += fmaxf(acc, 0.f) * W1b[c];
    }
    float d0 = b2b[0], d1 = b2b[1];
#pragma unroll 4
    for (int c = 0; c < 32; c++) {
        float acc = b2a[c];
#pragma unroll
        for (int k = 0; k < 32; k++) acc += p[k] * W2a[k * 32 + c];
        float t = fmaxf(acc, 0.f);
        d0 += t * W2b[c * 2];
        d1 += t * W2b[c * 2 + 1];
    }
    float mx = fmaxf(d0, d1);
    float ls = mx + logf(expf(d0 - mx) + expf(d1 - mx));
    dout[g] = lab;
    dout[GG + g * 2]     = d0 - ls;
    dout[GG + g * 2 + 1] = d1 - ls;
}

// ---------------------------------------------------------------------------
extern "C" void kernel_launch(void* const* d_in, const int* in_sizes, int n_in,
                              void* d_out, int out_size, void* d_ws, size_t ws_size,
                              hipStream_t stream) {
    const float* x   = (const float*)d_in[0];
    const float* ea  = (const float*)d_in[1];
    const int* ei    = (const int*)d_in[2];
    const int* batch = (const int*)d_in[3];
    const float* W0 = (const float*)d_in[5],  *b0 = (const float*)d_in[6];
    const float* We1 = (const float*)d_in[7], *be1 = (const float*)d_in[8];
    const float* We2 = (const float*)d_in[9], *be2 = (const float*)d_in[10];
    const float* Wroot = (const float*)d_in[11], *bconv = (const float*)d_in[12];
    const float* Wih = (const float*)d_in[13], *bih = (const float*)d_in[14];
    const float* Whh = (const float*)d_in[15], *bhh = (const float*)d_in[16];
    const float* W1a = (const float*)d_in[17], *b1a = (const float*)d_in[18];
    const float* W1b = (const float*)d_in[19], *b1b = (const float*)d_in[20];
    const float* W2a = (const float*)d_in[21], *b2a = (const float*)d_in[22];
    const float* W2b = (const float*)d_in[23], *b2b = (const float*)d_in[24];
    float* dout = (float*)d_out;

    char* w = (char*)d_ws;
    u16*   tmat = (u16*)w;    w += (size_t)EE * 32 * 2;   // 16,000,000
    u16*   Bg   = (u16*)w;    w += 33 * 1024 * 2 + 512;
    float* hf   = (float*)w;  w += (size_t)NN * 32 * 4;
    u16*   cur  = (u16*)w;    w += (size_t)NN * 32 * 2;
    float* agg  = (float*)w;  w += (size_t)NN * 32 * 4;
    float* dinv = (float*)w;  w += 200192;
    int*   degc = (int*)w;    w += 200192;
    float* gsum = (float*)w;  w += (size_t)GG * 32 * 4;
    int*   gcnt = (int*)w;    w += 2048;
    float4* wta_g = (float4*)w; w += 1024 * 16;           // 16 KB
    float2* wtb_g = (float2*)w; w += 1024 * 8;            //  8 KB

    hipMemsetAsync(degc, 0, NN * 4, stream);
    hipMemsetAsync(gcnt, 0, GG * 4, stream);
    hipMemsetAsync(gsum, 0, GG * 32 * 4, stream);

    prep_B<<<132, 256, 0, stream>>>(We2, be2, Bg);
    prep_WT<<<4, 256, 0, stream>>>(Wih, Whh, wta_g, wtb_g);
    prep_edges<<<(EE + 255) / 256, 256, 0, stream>>>(ea, We1, be1, tmat);
    lin0_k<<<(NN + 255) / 256, 256, 0, stream>>>(x, W0, b0, hf, cur);
    hist_k<<<(EE + 255) / 256, 256, 0, stream>>>(ei, batch, degc, gcnt);
    degfin_k<<<(NN + 255) / 256, 256, 0, stream>>>(degc, dinv);

    for (int it = 0; it < 3; it++) {
        hipMemsetAsync(agg, 0, (size_t)NN * 32 * 4, stream);
        msg_k<<<512, 512, 0, stream>>>(cur, tmat, ei, Bg, agg);
        node_update_v4<<<(NN + 63) / 64, 512, 0, stream>>>(hf, cur, agg, dinv,
                                                           Wroot, bconv, wta_g, wtb_g, bih, bhh);
    }

    pool_k<<<(NN + 255) / 256, 256, 0, stream>>>(hf, batch, gsum);
    head_k<<<2, 256, 0, stream>>>(gsum, gcnt, W1a, b1a, W1b, b1b, W2a, b2a, W2b, b2b, dout);
}

// Round 9
// 638.812 us; speedup vs baseline: 5.1816x; 1.1171x over previous
//
#include <hip/hip_runtime.h>

typedef unsigned short u16;
typedef unsigned int u32;

#define NN 50000
#define EE 250000
#define GG 512

typedef __bf16 bf16x8 __attribute__((ext_vector_type(8)));
typedef float  f32x4  __attribute__((ext_vector_type(4)));

__device__ __forceinline__ u16 f2bfu(float f) {
    __bf16 b = (__bf16)f; u16 u; __builtin_memcpy(&u, &b, 2); return u;
}
__device__ __forceinline__ float sigf(float x) { return 1.f / (1.f + expf(-x)); }

// ---------------------------------------------------------------------------
// Build swizzled B (We2 viewed as 1024x32, plus be2 as a 33rd K-step) in
// MFMA fragment order.
// ---------------------------------------------------------------------------
__global__ void prep_B(const float* __restrict__ We2, const float* __restrict__ be2,
                       u16* __restrict__ Bg) {
    int idx = blockIdx.x * blockDim.x + threadIdx.x;
    if (idx >= 33 * 1024) return;
    int kk = idx >> 10, off = idx & 1023;
    int ct = off >> 9, l = (off >> 3) & 63, j = off & 7;
    int q = l >> 4, c = l & 15, o = c + 16 * ct;
    float v;
    if (kk < 32) v = We2[(32 * kk + 8 * q + j) * 32 + o];
    else         v = be2[(8 * q + j) * 32 + o];
    Bg[idx] = f2bfu(v);
}

// ---------------------------------------------------------------------------
// Pack GRU gate weights (for node_update_v4)
// ---------------------------------------------------------------------------
__global__ void prep_WT(const float* __restrict__ Wih, const float* __restrict__ Whh,
                        float4* __restrict__ wta, float2* __restrict__ wtb) {
    int t = blockIdx.x * blockDim.x + threadIdx.x;
    if (t >= 1024) return;
    int k = t >> 5, j = t & 31;
    wta[t] = make_float4(Wih[j * 32 + k], Wih[(32 + j) * 32 + k],
                         Wih[(64 + j) * 32 + k], Whh[j * 32 + k]);
    wtb[t] = make_float2(Whh[(32 + j) * 32 + k], Whh[(64 + j) * 32 + k]);
}

// ---------------------------------------------------------------------------
// histograms: in-degree per node, node count per graph
// ---------------------------------------------------------------------------
__global__ void hist_k(const int* __restrict__ ei, const int* __restrict__ batch,
                       int* __restrict__ degc, int* __restrict__ gcnt) {
    int i = blockIdx.x * blockDim.x + threadIdx.x;
    if (i < EE) atomicAdd(degc + ei[EE + i], 1);
    if (i < NN) atomicAdd(gcnt + batch[i], 1);
}

// ---------------------------------------------------------------------------
// 2-level exclusive scan of degc -> cursor (CSR row starts)
// ---------------------------------------------------------------------------
__global__ __launch_bounds__(512) void scan_blk_k(const int* __restrict__ degc,
                                                  int* __restrict__ cursor,
                                                  int* __restrict__ bsum) {
    __shared__ int s[512];
    int tid = threadIdx.x, i = blockIdx.x * 512 + tid;
    int v = (i < NN) ? degc[i] : 0;
    s[tid] = v; __syncthreads();
#pragma unroll
    for (int off = 1; off < 512; off <<= 1) {
        int t2 = (tid >= off) ? s[tid - off] : 0;
        __syncthreads();
        s[tid] += t2;
        __syncthreads();
    }
    if (i < NN) cursor[i] = s[tid] - v;          // exclusive within block
    if (tid == 511) bsum[blockIdx.x] = s[511];
}

__global__ void scan_top_k(const int* __restrict__ bsum, int* __restrict__ boffs) {
    __shared__ int s[128];
    int tid = threadIdx.x;
    int v = (tid < 98) ? bsum[tid] : 0;
    s[tid] = v; __syncthreads();
#pragma unroll
    for (int off = 1; off < 128; off <<= 1) {
        int t2 = (tid >= off) ? s[tid - off] : 0;
        __syncthreads();
        s[tid] += t2;
        __syncthreads();
    }
    if (tid < 98) boffs[tid] = s[tid] - v;
}

__global__ __launch_bounds__(512) void scan_fix_k(int* __restrict__ cursor,
                                                  const int* __restrict__ boffs,
                                                  const int* __restrict__ degc,
                                                  float* __restrict__ dinv) {
    int i = blockIdx.x * 512 + threadIdx.x;
    if (i >= NN) return;
    cursor[i] += boffs[i >> 9];
    int c = degc[i];
    dinv[i] = 1.f / (float)(c > 0 ? c : 1);
}

// ---------------------------------------------------------------------------
// Scatter edges into dst-sorted order. posOf[e] = sorted slot of edge e.
// ---------------------------------------------------------------------------
__global__ void scatter_k(const int* __restrict__ ei, int* __restrict__ cursor,
                          int* __restrict__ posOf, int* __restrict__ srcs,
                          int* __restrict__ dsts) {
    int e = blockIdx.x * blockDim.x + threadIdx.x;
    if (e >= EE) return;
    int d = ei[EE + e];
    int p = atomicAdd(cursor + d, 1);
    posOf[e] = p;
    srcs[p] = ei[e];
    dsts[p] = d;
}

// ---------------------------------------------------------------------------
// t = relu(edge_attr @ We1 + be1), written bf16 at SORTED position
// ---------------------------------------------------------------------------
__global__ void prep_edges(const float* __restrict__ ea, const float* __restrict__ We1,
                           const float* __restrict__ be1, const int* __restrict__ posOf,
                           u16* __restrict__ tmat) {
    int e = blockIdx.x * blockDim.x + threadIdx.x;
    if (e >= EE) return;
    const float4* ep = (const float4*)(ea + (size_t)e * 16);
    float a[16];
#pragma unroll
    for (int i = 0; i < 4; i++) {
        float4 v = ep[i];
        a[4 * i] = v.x; a[4 * i + 1] = v.y; a[4 * i + 2] = v.z; a[4 * i + 3] = v.w;
    }
    u32 outw[16];
#pragma unroll
    for (int p = 0; p < 16; p++) {
        float acc0 = be1[2 * p], acc1 = be1[2 * p + 1];
#pragma unroll
        for (int k = 0; k < 16; k++) {
            acc0 += a[k] * We1[k * 32 + 2 * p];
            acc1 += a[k] * We1[k * 32 + 2 * p + 1];
        }
        acc0 = fmaxf(acc0, 0.f); acc1 = fmaxf(acc1, 0.f);
        outw[p] = (u32)f2bfu(acc0) | ((u32)f2bfu(acc1) << 16);
    }
    uint4* op = (uint4*)(tmat + (size_t)posOf[e] * 32);
#pragma unroll
    for (int i = 0; i < 4; i++)
        op[i] = make_uint4(outw[4 * i], outw[4 * i + 1], outw[4 * i + 2], outw[4 * i + 3]);
}

// ---------------------------------------------------------------------------
// h = relu(x @ W0 + b0); write f32 state + bf16 mirror
// ---------------------------------------------------------------------------
__global__ void lin0_k(const float* __restrict__ x, const float* __restrict__ W0,
                       const float* __restrict__ b0, float* __restrict__ hf,
                       u16* __restrict__ cur) {
    int n = blockIdx.x * blockDim.x + threadIdx.x;
    if (n >= NN) return;
    const float4* xp = (const float4*)(x + (size_t)n * 32);
    float a[32];
#pragma unroll
    for (int i = 0; i < 8; i++) {
        float4 v = xp[i];
        a[4 * i] = v.x; a[4 * i + 1] = v.y; a[4 * i + 2] = v.z; a[4 * i + 3] = v.w;
    }
    float o[32];
#pragma unroll 4
    for (int c = 0; c < 32; c++) {
        float acc = b0[c];
#pragma unroll
        for (int k = 0; k < 32; k++) acc += a[k] * W0[k * 32 + c];
        o[c] = fmaxf(acc, 0.f);
    }
    float4* hp = (float4*)(hf + (size_t)n * 32);
#pragma unroll
    for (int i = 0; i < 8; i++) hp[i] = make_float4(o[4 * i], o[4 * i + 1], o[4 * i + 2], o[4 * i + 3]);
    uint4* cp = (uint4*)(cur + (size_t)n * 32);
#pragma unroll
    for (int i = 0; i < 4; i++) {
        u32 p0 = (u32)f2bfu(o[8 * i + 0]) | ((u32)f2bfu(o[8 * i + 1]) << 16);
        u32 p1 = (u32)f2bfu(o[8 * i + 2]) | ((u32)f2bfu(o[8 * i + 3]) << 16);
        u32 p2 = (u32)f2bfu(o[8 * i + 4]) | ((u32)f2bfu(o[8 * i + 5]) << 16);
        u32 p3 = (u32)f2bfu(o[8 * i + 6]) | ((u32)f2bfu(o[8 * i + 7]) << 16);
        cp[i] = make_uint4(p0, p1, p2, p3);
    }
}

// ---------------------------------------------------------------------------
// Message kernel: dst-sorted edges; register-merge of equal-dst runs before
// atomics (static indexing only).
// ---------------------------------------------------------------------------
__global__ __launch_bounds__(512) void msg_k(const u16* __restrict__ cur,
                                             const u16* __restrict__ tmat,
                                             const int* __restrict__ srcs,
                                             const int* __restrict__ dsts,
                                             const u16* __restrict__ Bg,
                                             float* __restrict__ agg) {
    __shared__ uint4 Bl[4096];
    const uint4* Bgv = (const uint4*)Bg;
    for (int i = threadIdx.x; i < 4096; i += 512) Bl[i] = Bgv[i];
    __syncthreads();
    const u16* Bl16 = (const u16*)Bl;

    int l = threadIdx.x & 63;
    int q = l >> 4, r = l & 15;
    int wid = (blockIdx.x * blockDim.x + threadIdx.x) >> 6;
    int nw  = (gridDim.x * blockDim.x) >> 6;

    for (int tile = wid; tile < EE / 16; tile += nw) {
        int eb = tile * 16;
        int srow = srcs[eb + r];
        bf16x8 sv = *reinterpret_cast<const bf16x8*>(cur + (size_t)srow * 32 + q * 8);
        float sf[8];
#pragma unroll
        for (int j = 0; j < 8; j++) sf[j] = (float)sv[j];
        const uint4* tp = reinterpret_cast<const uint4*>(tmat + (size_t)(eb + r) * 32);
        f32x4 acc0 = {0.f, 0.f, 0.f, 0.f}, acc1 = {0.f, 0.f, 0.f, 0.f};
#pragma unroll
        for (int kq = 0; kq < 4; kq++) {
            uint4 tw4 = tp[kq];
            u32 tws[4] = {tw4.x, tw4.y, tw4.z, tw4.w};
#pragma unroll
            for (int du = 0; du < 4; du++) {
                u32 w = tws[du];
#pragma unroll
                for (int hl = 0; hl < 2; hl++) {
                    int kk = kq * 8 + du * 2 + hl;
                    float tf = __uint_as_float(hl ? (w & 0xffff0000u) : (w << 16));
                    bf16x8 av;
#pragma unroll
                    for (int j = 0; j < 8; j++) av[j] = (__bf16)(tf * sf[j]);
                    bf16x8 b0 = *reinterpret_cast<const bf16x8*>(Bl16 + kk * 1024 + l * 8);
                    bf16x8 b1 = *reinterpret_cast<const bf16x8*>(Bl16 + kk * 1024 + 512 + l * 8);
                    acc0 = __builtin_amdgcn_mfma_f32_16x16x32_bf16(av, b0, acc0, 0, 0, 0);
                    acc1 = __builtin_amdgcn_mfma_f32_16x16x32_bf16(av, b1, acc1, 0, 0, 0);
                }
            }
        }
        {
            bf16x8 b0 = *reinterpret_cast<const bf16x8*>(Bg + 32 * 1024 + l * 8);
            bf16x8 b1 = *reinterpret_cast<const bf16x8*>(Bg + 32 * 1024 + 512 + l * 8);
            acc0 = __builtin_amdgcn_mfma_f32_16x16x32_bf16(sv, b0, acc0, 0, 0, 0);
            acc1 = __builtin_amdgcn_mfma_f32_16x16x32_bf16(sv, b1, acc1, 0, 0, 0);
        }
        // C/D rows 4q+j are CONSECUTIVE sorted edges -> merge equal-dst runs.
        {
            int d0 = dsts[eb + 4 * q + 0], d1 = dsts[eb + 4 * q + 1];
            int d2 = dsts[eb + 4 * q + 2], d3 = dsts[eb + 4 * q + 3];
            float ca = acc0[0], cb = acc1[0];
            if (d0 != d1) {
                atomicAdd(agg + (size_t)d0 * 32 + r, ca);
                atomicAdd(agg + (size_t)d0 * 32 + 16 + r, cb);
                ca = 0.f; cb = 0.f;
            }
            ca += acc0[1]; cb += acc1[1];
            if (d1 != d2) {
                atomicAdd(agg + (size_t)d1 * 32 + r, ca);
                atomicAdd(agg + (size_t)d1 * 32 + 16 + r, cb);
                ca = 0.f; cb = 0.f;
            }
            ca += acc0[2]; cb += acc1[2];
            if (d2 != d3) {
                atomicAdd(agg + (size_t)d2 * 32 + r, ca);
                atomicAdd(agg + (size_t)d2 * 32 + 16 + r, cb);
                ca = 0.f; cb = 0.f;
            }
            ca += acc0[3]; cb += acc1[3];
            atomicAdd(agg + (size_t)d3 * 32 + r, ca);
            atomicAdd(agg + (size_t)d3 * 32 + 16 + r, cb);
        }
    }
}

// ---------------------------------------------------------------------------
// node_update_v4 (unchanged from round 8 — proven good)
// ---------------------------------------------------------------------------
__global__ __launch_bounds__(512) void node_update_v4(
        float* __restrict__ hf, u16* __restrict__ cur,
        const float* __restrict__ agg, const float* __restrict__ dinv,
        const float* __restrict__ Wroot, const float* __restrict__ bconv,
        const float4* __restrict__ wta_g, const float2* __restrict__ wtb_g,
        const float* __restrict__ bih, const float* __restrict__ bhh) {
    __shared__ float  wroot_l[1024];
    __shared__ float4 wta_l[1024];
    __shared__ float2 wtb_l[1024];
    __shared__ float  h_l[32 * 66];
    __shared__ float  m_l[32 * 66];
    __shared__ float  bias_l[192];

    const int t = threadIdx.x;
    const int w = t >> 6;
    const int lane = t & 63;
    const int nb = blockIdx.x * 64;
    const int n = nb + lane;
    const int nc = (n < NN) ? n : (NN - 1);

    if (t < 256) ((float4*)wroot_l)[t] = ((const float4*)Wroot)[t];
    wta_l[t] = wta_g[t]; wta_l[t + 512] = wta_g[t + 512];
    ((float4*)wtb_l)[t] = ((const float4*)wtb_g)[t];
    if (t < 192) bias_l[t] = (t < 96) ? bih[t] : bhh[t - 96];

    {
        const int nl = t >> 3, ch = t & 7;
        const int ng = nb + nl;
        const int ngc = (ng < NN) ? ng : (NN - 1);
        float4 v = *(const float4*)(hf + (size_t)ngc * 32 + ch * 4);
        h_l[(ch * 4 + 0) * 66 + nl] = v.x;
        h_l[(ch * 4 + 1) * 66 + nl] = v.y;
        h_l[(ch * 4 + 2) * 66 + nl] = v.z;
        h_l[(ch * 4 + 3) * 66 + nl] = v.w;
    }
    __syncthreads();

    const int c0 = w * 4;
    {
        const float di = dinv[nc];
        float4 ag = *(const float4*)(agg + (size_t)nc * 32 + c0);
        float a0 = bconv[c0 + 0] + ag.x * di;
        float a1 = bconv[c0 + 1] + ag.y * di;
        float a2 = bconv[c0 + 2] + ag.z * di;
        float a3 = bconv[c0 + 3] + ag.w * di;
#pragma unroll 4
        for (int k = 0; k < 32; k++) {
            float hk = h_l[k * 66 + lane];
            float4 wr = *(const float4*)&wroot_l[k * 32 + c0];
            a0 = fmaf(hk, wr.x, a0); a1 = fmaf(hk, wr.y, a1);
            a2 = fmaf(hk, wr.z, a2); a3 = fmaf(hk, wr.w, a3);
        }
        m_l[(c0 + 0) * 66 + lane] = fmaxf(a0, 0.f);
        m_l[(c0 + 1) * 66 + lane] = fmaxf(a1, 0.f);
        m_l[(c0 + 2) * 66 + lane] = fmaxf(a2, 0.f);
        m_l[(c0 + 3) * 66 + lane] = fmaxf(a3, 0.f);
    }
    __syncthreads();

    float outv[4];
#pragma unroll
    for (int half = 0; half < 2; half++) {
        const int j0 = c0 + half * 2;
        float air0 = 0.f, aiz0 = 0.f, ain0 = 0.f, ahr0 = 0.f, ahz0 = 0.f, ahn0 = 0.f;
        float air1 = 0.f, aiz1 = 0.f, ain1 = 0.f, ahr1 = 0.f, ahz1 = 0.f, ahn1 = 0.f;
#pragma unroll 4
        for (int k = 0; k < 32; k++) {
            float mk = m_l[k * 66 + lane];
            float hk = h_l[k * 66 + lane];
            float4 wa0 = wta_l[k * 32 + j0];
            float2 wb0 = wtb_l[k * 32 + j0];
            float4 wa1 = wta_l[k * 32 + j0 + 1];
            float2 wb1 = wtb_l[k * 32 + j0 + 1];
            air0 = fmaf(mk, wa0.x, air0); aiz0 = fmaf(mk, wa0.y, aiz0);
            ain0 = fmaf(mk, wa0.z, ain0); ahr0 = fmaf(hk, wa0.w, ahr0);
            ahz0 = fmaf(hk, wb0.x, ahz0); ahn0 = fmaf(hk, wb0.y, ahn0);
            air1 = fmaf(mk, wa1.x, air1); aiz1 = fmaf(mk, wa1.y, aiz1);
            ain1 = fmaf(mk, wa1.z, ain1); ahr1 = fmaf(hk, wa1.w, ahr1);
            ahz1 = fmaf(hk, wb1.x, ahz1); ahn1 = fmaf(hk, wb1.y, ahn1);
        }
#pragma unroll
        for (int jj = 0; jj < 2; jj++) {
            const int j = j0 + jj;
            float air = jj ? air1 : air0, aiz = jj ? aiz1 : aiz0, ain = jj ? ain1 : ain0;
            float ahr = jj ? ahr1 : ahr0, ahz = jj ? ahz1 : ahz0, ahn = jj ? ahn1 : ahn0;
            float r = sigf(air + ahr + bias_l[j] + bias_l[96 + j]);
            float z = sigf(aiz + ahz + bias_l[32 + j] + bias_l[128 + j]);
            float g = tanhf(ain + bias_l[64 + j] + r * (ahn + bias_l[160 + j]));
            float ho = h_l[j * 66 + lane];
            outv[half * 2 + jj] = (1.f - z) * g + z * ho;
        }
    }
    __syncthreads();

#pragma unroll
    for (int i = 0; i < 4; i++) m_l[(c0 + i) * 66 + lane] = outv[i];
    __syncthreads();

    {
        const int nl = t >> 3, q = (t & 7) * 4;
        const int ng = nb + nl;
        if (ng < NN) {
            float4 v = make_float4(m_l[(q + 0) * 66 + nl], m_l[(q + 1) * 66 + nl],
                                   m_l[(q + 2) * 66 + nl], m_l[(q + 3) * 66 + nl]);
            *(float4*)(hf + (size_t)ng * 32 + q) = v;
            u32 p0 = (u32)f2bfu(v.x) | ((u32)f2bfu(v.y) << 16);
            u32 p1 = (u32)f2bfu(v.z) | ((u32)f2bfu(v.w) << 16);
            *(uint2*)(cur + (size_t)ng * 32 + q) = make_uint2(p0, p1);
        }
    }
}

// ---------------------------------------------------------------------------
// pool_k2: run-length segmented reduction over sorted batch.
// Wave handles 256 consecutive nodes; lane -> (sub = lane>>5, col = lane&31).
// One atomic per (graph-run, col) instead of per (node, col).
// ---------------------------------------------------------------------------
__global__ __launch_bounds__(256) void pool_k2(const float* __restrict__ hf,
                                               const int* __restrict__ batch,
                                               float* __restrict__ gsum) {
    int wv = (blockIdx.x * 256 + threadIdx.x) >> 6;
    int lane = threadIdx.x & 63;
    int sub = lane >> 5, o = lane & 31;
    int base = wv * 256;
    if (base >= NN) return;
    float acc = 0.f; int gcur = -1;
#pragma unroll 4
    for (int i = 0; i < 128; i++) {
        int n = base + 2 * i + sub;
        if (n < NN) {
            int g = batch[n];
            float v = hf[(size_t)n * 32 + o];
            if (g != gcur) {
                if (gcur >= 0) atomicAdd(gsum + gcur * 32 + o, acc);
                gcur = g; acc = v;
            } else {
                acc += v;
            }
        }
    }
    if (gcur >= 0) atomicAdd(gsum + gcur * 32 + o, acc);
}

// ---------------------------------------------------------------------------
// Heads: OUTPUT IS FLOAT32
// ---------------------------------------------------------------------------
__global__ void head_k(const float* __restrict__ gsum, const int* __restrict__ gcnt,
                       const float* __restrict__ W1a, const float* __restrict__ b1a,
                       const float* __restrict__ W1b, const float* __restrict__ b1b,
                       const float* __restrict__ W2a, const float* __restrict__ b2a,
                       const float* __restrict__ W2b, const float* __restrict__ b2b,
                       float* __restrict__ dout) {
    int g = blockIdx.x * blockDim.x + threadIdx.x;
    if (g >= GG) return;
    int c0 = gcnt[g];
    float rc = 1.f / (float)(c0 > 0 ? c0 : 1);
    float p[32];
#pragma unroll
    for (int i = 0; i < 32; i++) p[i] = gsum[g * 32 + i] * rc;
    float lab = b1b[0];
#pragma unroll 4
    for (int c = 0; c < 32; c++) {
        float acc = b1a[c];
#pragma unroll
        for (int k = 0; k < 32; k++) acc += p[k] * W1a[k * 32 + c];
        lab += fmaxf(acc, 0.f) * W1b[c];
    }
    float d0 = b2b[0], d1 = b2b[1];
#pragma unroll 4
    for (int c = 0; c < 32; c++) {
        float acc = b2a[c];
#pragma unroll
        for (int k = 0; k < 32; k++) acc += p[k] * W2a[k * 32 + c];
        float t = fmaxf(acc, 0.f);
        d0 += t * W2b[c * 2];
        d1 += t * W2b[c * 2 + 1];
    }
    float mx = fmaxf(d0, d1);
    float ls = mx + logf(expf(d0 - mx) + expf(d1 - mx));
    dout[g] = lab;
    dout[GG + g * 2]     = d0 - ls;
    dout[GG + g * 2 + 1] = d1 - ls;
}

// ---------------------------------------------------------------------------
extern "C" void kernel_launch(void* const* d_in, const int* in_sizes, int n_in,
                              void* d_out, int out_size, void* d_ws, size_t ws_size,
                              hipStream_t stream) {
    const float* x   = (const float*)d_in[0];
    const float* ea  = (const float*)d_in[1];
    const int* ei    = (const int*)d_in[2];
    const int* batch = (const int*)d_in[3];
    const float* W0 = (const float*)d_in[5],  *b0 = (const float*)d_in[6];
    const float* We1 = (const float*)d_in[7], *be1 = (const float*)d_in[8];
    const float* We2 = (const float*)d_in[9], *be2 = (const float*)d_in[10];
    const float* Wroot = (const float*)d_in[11], *bconv = (const float*)d_in[12];
    const float* Wih = (const float*)d_in[13], *bih = (const float*)d_in[14];
    const float* Whh = (const float*)d_in[15], *bhh = (const float*)d_in[16];
    const float* W1a = (const float*)d_in[17], *b1a = (const float*)d_in[18];
    const float* W1b = (const float*)d_in[19], *b1b = (const float*)d_in[20];
    const float* W2a = (const float*)d_in[21], *b2a = (const float*)d_in[22];
    const float* W2b = (const float*)d_in[23], *b2b = (const float*)d_in[24];
    float* dout = (float*)d_out;

    char* w = (char*)d_ws;
    u16*   tmat = (u16*)w;    w += (size_t)EE * 32 * 2;   // 16,000,000
    u16*   Bg   = (u16*)w;    w += 33 * 1024 * 2 + 512;
    float* hf   = (float*)w;  w += (size_t)NN * 32 * 4;
    u16*   cur  = (u16*)w;    w += (size_t)NN * 32 * 2;
    float* agg  = (float*)w;  w += (size_t)NN * 32 * 4;
    float* dinv = (float*)w;  w += 200192;
    int*   degc = (int*)w;    w += 200192;
    float* gsum = (float*)w;  w += (size_t)GG * 32 * 4;
    int*   gcnt = (int*)w;    w += 2048;
    float4* wta_g = (float4*)w; w += 1024 * 16;
    float2* wtb_g = (float2*)w; w += 1024 * 8;
    int*   cursor = (int*)w;  w += 200192;
    int*   posOf  = (int*)w;  w += (size_t)EE * 4;
    int*   srcs   = (int*)w;  w += (size_t)EE * 4;
    int*   dsts   = (int*)w;  w += (size_t)EE * 4;
    int*   bsum   = (int*)w;  w += 512;
    int*   boffs  = (int*)w;  w += 512;

    hipMemsetAsync(degc, 0, NN * 4, stream);
    hipMemsetAsync(gcnt, 0, GG * 4, stream);
    hipMemsetAsync(gsum, 0, GG * 32 * 4, stream);

    // CSR build: hist -> scan -> scatter (dst-sorted edge order)
    hist_k<<<(EE + 255) / 256, 256, 0, stream>>>(ei, batch, degc, gcnt);
    scan_blk_k<<<98, 512, 0, stream>>>(degc, cursor, bsum);
    scan_top_k<<<1, 128, 0, stream>>>(bsum, boffs);
    scan_fix_k<<<98, 512, 0, stream>>>(cursor, boffs, degc, dinv);
    scatter_k<<<(EE + 255) / 256, 256, 0, stream>>>(ei, cursor, posOf, srcs, dsts);

    prep_B<<<132, 256, 0, stream>>>(We2, be2, Bg);
    prep_WT<<<4, 256, 0, stream>>>(Wih, Whh, wta_g, wtb_g);
    prep_edges<<<(EE + 255) / 256, 256, 0, stream>>>(ea, We1, be1, posOf, tmat);
    lin0_k<<<(NN + 255) / 256, 256, 0, stream>>>(x, W0, b0, hf, cur);

    for (int it = 0; it < 3; it++) {
        hipMemsetAsync(agg, 0, (size_t)NN * 32 * 4, stream);
        msg_k<<<512, 512, 0, stream>>>(cur, tmat, srcs, dsts, Bg, agg);
        node_update_v4<<<(NN + 63) / 64, 512, 0, stream>>>(hf, cur, agg, dinv,
                                                           Wroot, bconv, wta_g, wtb_g, bih, bhh);
    }

    pool_k2<<<49, 256, 0, stream>>>(hf, batch, gsum);
    head_k<<<2, 256, 0, stream>>>(gsum, gcnt, W1a, b1a, W1b, b1b, W2a, b2a, W2b, b2b, dout);
}

// Round 10
// 618.324 us; speedup vs baseline: 5.3533x; 1.0331x over previous
//
#include <hip/hip_runtime.h>

typedef unsigned short u16;
typedef unsigned int u32;

#define NN 50000
#define EE 250000
#define GG 512

typedef __bf16 bf16x8 __attribute__((ext_vector_type(8)));
typedef float  f32x4  __attribute__((ext_vector_type(4)));

__device__ __forceinline__ u16 f2bfu(float f) {
    __bf16 b = (__bf16)f; u16 u; __builtin_memcpy(&u, &b, 2); return u;
}
__device__ __forceinline__ float sigf(float x) { return 1.f / (1.f + expf(-x)); }

// ---------------------------------------------------------------------------
// Build swizzled B (We2 viewed as 1024x32, plus be2 as a 33rd K-step) in
// MFMA fragment order.
// ---------------------------------------------------------------------------
__global__ void prep_B(const float* __restrict__ We2, const float* __restrict__ be2,
                       u16* __restrict__ Bg) {
    int idx = blockIdx.x * blockDim.x + threadIdx.x;
    if (idx >= 33 * 1024) return;
    int kk = idx >> 10, off = idx & 1023;
    int ct = off >> 9, l = (off >> 3) & 63, j = off & 7;
    int q = l >> 4, c = l & 15, o = c + 16 * ct;
    float v;
    if (kk < 32) v = We2[(32 * kk + 8 * q + j) * 32 + o];
    else         v = be2[(8 * q + j) * 32 + o];
    Bg[idx] = f2bfu(v);
}

// ---------------------------------------------------------------------------
// Pack GRU gate weights (for node_update_v4)
// ---------------------------------------------------------------------------
__global__ void prep_WT(const float* __restrict__ Wih, const float* __restrict__ Whh,
                        float4* __restrict__ wta, float2* __restrict__ wtb) {
    int t = blockIdx.x * blockDim.x + threadIdx.x;
    if (t >= 1024) return;
    int k = t >> 5, j = t & 31;
    wta[t] = make_float4(Wih[j * 32 + k], Wih[(32 + j) * 32 + k],
                         Wih[(64 + j) * 32 + k], Whh[j * 32 + k]);
    wtb[t] = make_float2(Whh[(32 + j) * 32 + k], Whh[(64 + j) * 32 + k]);
}

// ---------------------------------------------------------------------------
// histograms: in-degree per node, node count per graph
// ---------------------------------------------------------------------------
__global__ void hist_k(const int* __restrict__ ei, const int* __restrict__ batch,
                       int* __restrict__ degc, int* __restrict__ gcnt) {
    int i = blockIdx.x * blockDim.x + threadIdx.x;
    if (i < EE) atomicAdd(degc + ei[EE + i], 1);
    if (i < NN) atomicAdd(gcnt + batch[i], 1);
}

// ---------------------------------------------------------------------------
// 2-level exclusive scan of degc -> cursor (CSR row starts)
// ---------------------------------------------------------------------------
__global__ __launch_bounds__(512) void scan_blk_k(const int* __restrict__ degc,
                                                  int* __restrict__ cursor,
                                                  int* __restrict__ bsum) {
    __shared__ int s[512];
    int tid = threadIdx.x, i = blockIdx.x * 512 + tid;
    int v = (i < NN) ? degc[i] : 0;
    s[tid] = v; __syncthreads();
#pragma unroll
    for (int off = 1; off < 512; off <<= 1) {
        int t2 = (tid >= off) ? s[tid - off] : 0;
        __syncthreads();
        s[tid] += t2;
        __syncthreads();
    }
    if (i < NN) cursor[i] = s[tid] - v;          // exclusive within block
    if (tid == 511) bsum[blockIdx.x] = s[511];
}

__global__ void scan_top_k(const int* __restrict__ bsum, int* __restrict__ boffs) {
    __shared__ int s[128];
    int tid = threadIdx.x;
    int v = (tid < 98) ? bsum[tid] : 0;
    s[tid] = v; __syncthreads();
#pragma unroll
    for (int off = 1; off < 128; off <<= 1) {
        int t2 = (tid >= off) ? s[tid - off] : 0;
        __syncthreads();
        s[tid] += t2;
        __syncthreads();
    }
    if (tid < 98) boffs[tid] = s[tid] - v;
}

// also saves row starts (rs, with rs[NN]=EE) and computes dinv
__global__ __launch_bounds__(512) void scan_fix_k(int* __restrict__ cursor,
                                                  const int* __restrict__ boffs,
                                                  const int* __restrict__ degc,
                                                  float* __restrict__ dinv,
                                                  int* __restrict__ rs) {
    int i = blockIdx.x * 512 + threadIdx.x;
    if (i >= NN) return;
    int v = cursor[i] + boffs[i >> 9];
    cursor[i] = v;
    rs[i] = v;
    if (i == NN - 1) rs[NN] = EE;
    int c = degc[i];
    dinv[i] = 1.f / (float)(c > 0 ? c : 1);
}

// ---------------------------------------------------------------------------
// Scatter edges into dst-sorted order. posOf[e] = sorted slot of edge e.
// ---------------------------------------------------------------------------
__global__ void scatter_k(const int* __restrict__ ei, int* __restrict__ cursor,
                          int* __restrict__ posOf, int* __restrict__ srcs) {
    int e = blockIdx.x * blockDim.x + threadIdx.x;
    if (e >= EE) return;
    int d = ei[EE + e];
    int p = atomicAdd(cursor + d, 1);
    posOf[e] = p;
    srcs[p] = ei[e];
}

// ---------------------------------------------------------------------------
// t = relu(edge_attr @ We1 + be1), written bf16 at SORTED position
// ---------------------------------------------------------------------------
__global__ void prep_edges(const float* __restrict__ ea, const float* __restrict__ We1,
                           const float* __restrict__ be1, const int* __restrict__ posOf,
                           u16* __restrict__ tmat) {
    int e = blockIdx.x * blockDim.x + threadIdx.x;
    if (e >= EE) return;
    const float4* ep = (const float4*)(ea + (size_t)e * 16);
    float a[16];
#pragma unroll
    for (int i = 0; i < 4; i++) {
        float4 v = ep[i];
        a[4 * i] = v.x; a[4 * i + 1] = v.y; a[4 * i + 2] = v.z; a[4 * i + 3] = v.w;
    }
    u32 outw[16];
#pragma unroll
    for (int p = 0; p < 16; p++) {
        float acc0 = be1[2 * p], acc1 = be1[2 * p + 1];
#pragma unroll
        for (int k = 0; k < 16; k++) {
            acc0 += a[k] * We1[k * 32 + 2 * p];
            acc1 += a[k] * We1[k * 32 + 2 * p + 1];
        }
        acc0 = fmaxf(acc0, 0.f); acc1 = fmaxf(acc1, 0.f);
        outw[p] = (u32)f2bfu(acc0) | ((u32)f2bfu(acc1) << 16);
    }
    uint4* op = (uint4*)(tmat + (size_t)posOf[e] * 32);
#pragma unroll
    for (int i = 0; i < 4; i++)
        op[i] = make_uint4(outw[4 * i], outw[4 * i + 1], outw[4 * i + 2], outw[4 * i + 3]);
}

// ---------------------------------------------------------------------------
// h = relu(x @ W0 + b0); write f32 state + bf16 mirror
// ---------------------------------------------------------------------------
__global__ void lin0_k(const float* __restrict__ x, const float* __restrict__ W0,
                       const float* __restrict__ b0, float* __restrict__ hf,
                       u16* __restrict__ cur) {
    int n = blockIdx.x * blockDim.x + threadIdx.x;
    if (n >= NN) return;
    const float4* xp = (const float4*)(x + (size_t)n * 32);
    float a[32];
#pragma unroll
    for (int i = 0; i < 8; i++) {
        float4 v = xp[i];
        a[4 * i] = v.x; a[4 * i + 1] = v.y; a[4 * i + 2] = v.z; a[4 * i + 3] = v.w;
    }
    float o[32];
#pragma unroll 4
    for (int c = 0; c < 32; c++) {
        float acc = b0[c];
#pragma unroll
        for (int k = 0; k < 32; k++) acc += a[k] * W0[k * 32 + c];
        o[c] = fmaxf(acc, 0.f);
    }
    float4* hp = (float4*)(hf + (size_t)n * 32);
#pragma unroll
    for (int i = 0; i < 8; i++) hp[i] = make_float4(o[4 * i], o[4 * i + 1], o[4 * i + 2], o[4 * i + 3]);
    uint4* cp = (uint4*)(cur + (size_t)n * 32);
#pragma unroll
    for (int i = 0; i < 4; i++) {
        u32 p0 = (u32)f2bfu(o[8 * i + 0]) | ((u32)f2bfu(o[8 * i + 1]) << 16);
        u32 p1 = (u32)f2bfu(o[8 * i + 2]) | ((u32)f2bfu(o[8 * i + 3]) << 16);
        u32 p2 = (u32)f2bfu(o[8 * i + 4]) | ((u32)f2bfu(o[8 * i + 5]) << 16);
        u32 p3 = (u32)f2bfu(o[8 * i + 6]) | ((u32)f2bfu(o[8 * i + 7]) << 16);
        cp[i] = make_uint4(p0, p1, p2, p3);
    }
}

// ---------------------------------------------------------------------------
// Message kernel v2: dst-sorted edges; epilogue = plain coalesced stores of
// per-edge messages into msgf (NO atomics, no RMW).
// ---------------------------------------------------------------------------
__global__ __launch_bounds__(512) void msg_k(const u16* __restrict__ cur,
                                             const u16* __restrict__ tmat,
                                             const int* __restrict__ srcs,
                                             const u16* __restrict__ Bg,
                                             float* __restrict__ msgf) {
    __shared__ uint4 Bl[4096];
    const uint4* Bgv = (const uint4*)Bg;
    for (int i = threadIdx.x; i < 4096; i += 512) Bl[i] = Bgv[i];
    __syncthreads();
    const u16* Bl16 = (const u16*)Bl;

    int l = threadIdx.x & 63;
    int q = l >> 4, r = l & 15;
    int wid = (blockIdx.x * blockDim.x + threadIdx.x) >> 6;
    int nw  = (gridDim.x * blockDim.x) >> 6;

    for (int tile = wid; tile < EE / 16; tile += nw) {
        int eb = tile * 16;
        int srow = srcs[eb + r];
        bf16x8 sv = *reinterpret_cast<const bf16x8*>(cur + (size_t)srow * 32 + q * 8);
        float sf[8];
#pragma unroll
        for (int j = 0; j < 8; j++) sf[j] = (float)sv[j];
        const uint4* tp = reinterpret_cast<const uint4*>(tmat + (size_t)(eb + r) * 32);
        f32x4 acc0 = {0.f, 0.f, 0.f, 0.f}, acc1 = {0.f, 0.f, 0.f, 0.f};
#pragma unroll
        for (int kq = 0; kq < 4; kq++) {
            uint4 tw4 = tp[kq];
            u32 tws[4] = {tw4.x, tw4.y, tw4.z, tw4.w};
#pragma unroll
            for (int du = 0; du < 4; du++) {
                u32 w = tws[du];
#pragma unroll
                for (int hl = 0; hl < 2; hl++) {
                    int kk = kq * 8 + du * 2 + hl;
                    float tf = __uint_as_float(hl ? (w & 0xffff0000u) : (w << 16));
                    bf16x8 av;
#pragma unroll
                    for (int j = 0; j < 8; j++) av[j] = (__bf16)(tf * sf[j]);
                    bf16x8 b0 = *reinterpret_cast<const bf16x8*>(Bl16 + kk * 1024 + l * 8);
                    bf16x8 b1 = *reinterpret_cast<const bf16x8*>(Bl16 + kk * 1024 + 512 + l * 8);
                    acc0 = __builtin_amdgcn_mfma_f32_16x16x32_bf16(av, b0, acc0, 0, 0, 0);
                    acc1 = __builtin_amdgcn_mfma_f32_16x16x32_bf16(av, b1, acc1, 0, 0, 0);
                }
            }
        }
        {
            bf16x8 b0 = *reinterpret_cast<const bf16x8*>(Bg + 32 * 1024 + l * 8);
            bf16x8 b1 = *reinterpret_cast<const bf16x8*>(Bg + 32 * 1024 + 512 + l * 8);
            acc0 = __builtin_amdgcn_mfma_f32_16x16x32_bf16(sv, b0, acc0, 0, 0, 0);
            acc1 = __builtin_amdgcn_mfma_f32_16x16x32_bf16(sv, b1, acc1, 0, 0, 0);
        }
        // C/D: lane (q,r) reg j -> sorted edge row eb+4q+j, col r / r+16.
        // 16-lane r-groups store contiguous 64B lines. No atomics.
        {
            float* mp = msgf + (size_t)eb * 32;
#pragma unroll
            for (int j = 0; j < 4; j++) {
                mp[(4 * q + j) * 32 + r]      = acc0[j];
                mp[(4 * q + j) * 32 + 16 + r] = acc1[j];
            }
        }
    }
}

// ---------------------------------------------------------------------------
// reduce_k: CSR segmented sum. thread = (node, col-quad of 8).
// Reads node's contiguous msg rows (streaming), writes agg non-atomically.
// ---------------------------------------------------------------------------
__global__ __launch_bounds__(256) void reduce_k(const float* __restrict__ msgf,
                                                const int* __restrict__ rs,
                                                float* __restrict__ agg) {
    int t = blockIdx.x * 256 + threadIdx.x;
    int n = t >> 2, qd = t & 3;
    if (n >= NN) return;
    int p0 = rs[n], p1 = rs[n + 1];
    float a0 = 0.f, a1 = 0.f, a2 = 0.f, a3 = 0.f;
    float b0 = 0.f, b1 = 0.f, b2 = 0.f, b3 = 0.f;
    for (int p = p0; p < p1; p++) {
        const float4* mp = (const float4*)(msgf + (size_t)p * 32 + qd * 8);
        float4 v0 = mp[0], v1 = mp[1];
        a0 += v0.x; a1 += v0.y; a2 += v0.z; a3 += v0.w;
        b0 += v1.x; b1 += v1.y; b2 += v1.z; b3 += v1.w;
    }
    float4* ap = (float4*)(agg + (size_t)n * 32 + qd * 8);
    ap[0] = make_float4(a0, a1, a2, a3);
    ap[1] = make_float4(b0, b1, b2, b3);
}

// ---------------------------------------------------------------------------
// node_update_v4 (unchanged — proven good)
// ---------------------------------------------------------------------------
__global__ __launch_bounds__(512) void node_update_v4(
        float* __restrict__ hf, u16* __restrict__ cur,
        const float* __restrict__ agg, const float* __restrict__ dinv,
        const float* __restrict__ Wroot, const float* __restrict__ bconv,
        const float4* __restrict__ wta_g, const float2* __restrict__ wtb_g,
        const float* __restrict__ bih, const float* __restrict__ bhh) {
    __shared__ float  wroot_l[1024];
    __shared__ float4 wta_l[1024];
    __shared__ float2 wtb_l[1024];
    __shared__ float  h_l[32 * 66];
    __shared__ float  m_l[32 * 66];
    __shared__ float  bias_l[192];

    const int t = threadIdx.x;
    const int w = t >> 6;
    const int lane = t & 63;
    const int nb = blockIdx.x * 64;
    const int n = nb + lane;
    const int nc = (n < NN) ? n : (NN - 1);

    if (t < 256) ((float4*)wroot_l)[t] = ((const float4*)Wroot)[t];
    wta_l[t] = wta_g[t]; wta_l[t + 512] = wta_g[t + 512];
    ((float4*)wtb_l)[t] = ((const float4*)wtb_g)[t];
    if (t < 192) bias_l[t] = (t < 96) ? bih[t] : bhh[t - 96];

    {
        const int nl = t >> 3, ch = t & 7;
        const int ng = nb + nl;
        const int ngc = (ng < NN) ? ng : (NN - 1);
        float4 v = *(const float4*)(hf + (size_t)ngc * 32 + ch * 4);
        h_l[(ch * 4 + 0) * 66 + nl] = v.x;
        h_l[(ch * 4 + 1) * 66 + nl] = v.y;
        h_l[(ch * 4 + 2) * 66 + nl] = v.z;
        h_l[(ch * 4 + 3) * 66 + nl] = v.w;
    }
    __syncthreads();

    const int c0 = w * 4;
    {
        const float di = dinv[nc];
        float4 ag = *(const float4*)(agg + (size_t)nc * 32 + c0);
        float a0 = bconv[c0 + 0] + ag.x * di;
        float a1 = bconv[c0 + 1] + ag.y * di;
        float a2 = bconv[c0 + 2] + ag.z * di;
        float a3 = bconv[c0 + 3] + ag.w * di;
#pragma unroll 4
        for (int k = 0; k < 32; k++) {
            float hk = h_l[k * 66 + lane];
            float4 wr = *(const float4*)&wroot_l[k * 32 + c0];
            a0 = fmaf(hk, wr.x, a0); a1 = fmaf(hk, wr.y, a1);
            a2 = fmaf(hk, wr.z, a2); a3 = fmaf(hk, wr.w, a3);
        }
        m_l[(c0 + 0) * 66 + lane] = fmaxf(a0, 0.f);
        m_l[(c0 + 1) * 66 + lane] = fmaxf(a1, 0.f);
        m_l[(c0 + 2) * 66 + lane] = fmaxf(a2, 0.f);
        m_l[(c0 + 3) * 66 + lane] = fmaxf(a3, 0.f);
    }
    __syncthreads();

    float outv[4];
#pragma unroll
    for (int half = 0; half < 2; half++) {
        const int j0 = c0 + half * 2;
        float air0 = 0.f, aiz0 = 0.f, ain0 = 0.f, ahr0 = 0.f, ahz0 = 0.f, ahn0 = 0.f;
        float air1 = 0.f, aiz1 = 0.f, ain1 = 0.f, ahr1 = 0.f, ahz1 = 0.f, ahn1 = 0.f;
#pragma unroll 4
        for (int k = 0; k < 32; k++) {
            float mk = m_l[k * 66 + lane];
            float hk = h_l[k * 66 + lane];
            float4 wa0 = wta_l[k * 32 + j0];
            float2 wb0 = wtb_l[k * 32 + j0];
            float4 wa1 = wta_l[k * 32 + j0 + 1];
            float2 wb1 = wtb_l[k * 32 + j0 + 1];
            air0 = fmaf(mk, wa0.x, air0); aiz0 = fmaf(mk, wa0.y, aiz0);
            ain0 = fmaf(mk, wa0.z, ain0); ahr0 = fmaf(hk, wa0.w, ahr0);
            ahz0 = fmaf(hk, wb0.x, ahz0); ahn0 = fmaf(hk, wb0.y, ahn0);
            air1 = fmaf(mk, wa1.x, air1); aiz1 = fmaf(mk, wa1.y, aiz1);
            ain1 = fmaf(mk, wa1.z, ain1); ahr1 = fmaf(hk, wa1.w, ahr1);
            ahz1 = fmaf(hk, wb1.x, ahz1); ahn1 = fmaf(hk, wb1.y, ahn1);
        }
#pragma unroll
        for (int jj = 0; jj < 2; jj++) {
            const int j = j0 + jj;
            float air = jj ? air1 : air0, aiz = jj ? aiz1 : aiz0, ain = jj ? ain1 : ain0;
            float ahr = jj ? ahr1 : ahr0, ahz = jj ? ahz1 : ahz0, ahn = jj ? ahn1 : ahn0;
            float r = sigf(air + ahr + bias_l[j] + bias_l[96 + j]);
            float z = sigf(aiz + ahz + bias_l[32 + j] + bias_l[128 + j]);
            float g = tanhf(ain + bias_l[64 + j] + r * (ahn + bias_l[160 + j]));
            float ho = h_l[j * 66 + lane];
            outv[half * 2 + jj] = (1.f - z) * g + z * ho;
        }
    }
    __syncthreads();

#pragma unroll
    for (int i = 0; i < 4; i++) m_l[(c0 + i) * 66 + lane] = outv[i];
    __syncthreads();

    {
        const int nl = t >> 3, q = (t & 7) * 4;
        const int ng = nb + nl;
        if (ng < NN) {
            float4 v = make_float4(m_l[(q + 0) * 66 + nl], m_l[(q + 1) * 66 + nl],
                                   m_l[(q + 2) * 66 + nl], m_l[(q + 3) * 66 + nl]);
            *(float4*)(hf + (size_t)ng * 32 + q) = v;
            u32 p0 = (u32)f2bfu(v.x) | ((u32)f2bfu(v.y) << 16);
            u32 p1 = (u32)f2bfu(v.z) | ((u32)f2bfu(v.w) << 16);
            *(uint2*)(cur + (size_t)ng * 32 + q) = make_uint2(p0, p1);
        }
    }
}

// ---------------------------------------------------------------------------
// pool_k2: run-length segmented reduction over sorted batch.
// ---------------------------------------------------------------------------
__global__ __launch_bounds__(256) void pool_k2(const float* __restrict__ hf,
                                               const int* __restrict__ batch,
                                               float* __restrict__ gsum) {
    int wv = (blockIdx.x * 256 + threadIdx.x) >> 6;
    int lane = threadIdx.x & 63;
    int sub = lane >> 5, o = lane & 31;
    int base = wv * 256;
    if (base >= NN) return;
    float acc = 0.f; int gcur = -1;
#pragma unroll 4
    for (int i = 0; i < 128; i++) {
        int n = base + 2 * i + sub;
        if (n < NN) {
            int g = batch[n];
            float v = hf[(size_t)n * 32 + o];
            if (g != gcur) {
                if (gcur >= 0) atomicAdd(gsum + gcur * 32 + o, acc);
                gcur = g; acc = v;
            } else {
                acc += v;
            }
        }
    }
    if (gcur >= 0) atomicAdd(gsum + gcur * 32 + o, acc);
}

// ---------------------------------------------------------------------------
// Heads: OUTPUT IS FLOAT32
// ---------------------------------------------------------------------------
__global__ void head_k(const float* __restrict__ gsum, const int* __restrict__ gcnt,
                       const float* __restrict__ W1a, const float* __restrict__ b1a,
                       const float* __restrict__ W1b, const float* __restrict__ b1b,
                       const float* __restrict__ W2a, const float* __restrict__ b2a,
                       const float* __restrict__ W2b, const float* __restrict__ b2b,
                       float* __restrict__ dout) {
    int g = blockIdx.x * blockDim.x + threadIdx.x;
    if (g >= GG) return;
    int c0 = gcnt[g];
    float rc = 1.f / (float)(c0 > 0 ? c0 : 1);
    float p[32];
#pragma unroll
    for (int i = 0; i < 32; i++) p[i] = gsum[g * 32 + i] * rc;
    float lab = b1b[0];
#pragma unroll 4
    for (int c = 0; c < 32; c++) {
        float acc = b1a[c];
#pragma unroll
        for (int k = 0; k < 32; k++) acc += p[k] * W1a[k * 32 + c];
        lab += fmaxf(acc, 0.f) * W1b[c];
    }
    float d0 = b2b[0], d1 = b2b[1];
#pragma unroll 4
    for (int c = 0; c < 32; c++) {
        float acc = b2a[c];
#pragma unroll
        for (int k = 0; k < 32; k++) acc += p[k] * W2a[k * 32 + c];
        float t = fmaxf(acc, 0.f);
        d0 += t * W2b[c * 2];
        d1 += t * W2b[c * 2 + 1];
    }
    float mx = fmaxf(d0, d1);
    float ls = mx + logf(expf(d0 - mx) + expf(d1 - mx));
    dout[g] = lab;
    dout[GG + g * 2]     = d0 - ls;
    dout[GG + g * 2 + 1] = d1 - ls;
}

// ---------------------------------------------------------------------------
extern "C" void kernel_launch(void* const* d_in, const int* in_sizes, int n_in,
                              void* d_out, int out_size, void* d_ws, size_t ws_size,
                              hipStream_t stream) {
    const float* x   = (const float*)d_in[0];
    const float* ea  = (const float*)d_in[1];
    const int* ei    = (const int*)d_in[2];
    const int* batch = (const int*)d_in[3];
    const float* W0 = (const float*)d_in[5],  *b0 = (const float*)d_in[6];
    const float* We1 = (const float*)d_in[7], *be1 = (const float*)d_in[8];
    const float* We2 = (const float*)d_in[9], *be2 = (const float*)d_in[10];
    const float* Wroot = (const float*)d_in[11], *bconv = (const float*)d_in[12];
    const float* Wih = (const float*)d_in[13], *bih = (const float*)d_in[14];
    const float* Whh = (const float*)d_in[15], *bhh = (const float*)d_in[16];
    const float* W1a = (const float*)d_in[17], *b1a = (const float*)d_in[18];
    const float* W1b = (const float*)d_in[19], *b1b = (const float*)d_in[20];
    const float* W2a = (const float*)d_in[21], *b2a = (const float*)d_in[22];
    const float* W2b = (const float*)d_in[23], *b2b = (const float*)d_in[24];
    float* dout = (float*)d_out;

    char* w = (char*)d_ws;
    u16*   tmat = (u16*)w;    w += (size_t)EE * 32 * 2;   // 16,000,000
    u16*   Bg   = (u16*)w;    w += 33 * 1024 * 2 + 512;
    float* hf   = (float*)w;  w += (size_t)NN * 32 * 4;
    u16*   cur  = (u16*)w;    w += (size_t)NN * 32 * 2;
    float* agg  = (float*)w;  w += (size_t)NN * 32 * 4;
    float* dinv = (float*)w;  w += 200192;
    int*   degc = (int*)w;    w += 200192;
    float* gsum = (float*)w;  w += (size_t)GG * 32 * 4;
    int*   gcnt = (int*)w;    w += 2048;
    float4* wta_g = (float4*)w; w += 1024 * 16;
    float2* wtb_g = (float2*)w; w += 1024 * 8;
    int*   cursor = (int*)w;  w += 200192;
    int*   posOf  = (int*)w;  w += (size_t)EE * 4;
    int*   srcs   = (int*)w;  w += (size_t)EE * 4;
    int*   rs     = (int*)w;  w += 200192;               // NN+1 row starts
    int*   bsum   = (int*)w;  w += 512;
    int*   boffs  = (int*)w;  w += 512;
    float* msgf   = (float*)w; w += (size_t)EE * 32 * 4; // 32,000,000

    hipMemsetAsync(degc, 0, NN * 4, stream);
    hipMemsetAsync(gcnt, 0, GG * 4, stream);
    hipMemsetAsync(gsum, 0, GG * 32 * 4, stream);

    // CSR build: hist -> scan -> scatter (dst-sorted edge order)
    hist_k<<<(EE + 255) / 256, 256, 0, stream>>>(ei, batch, degc, gcnt);
    scan_blk_k<<<98, 512, 0, stream>>>(degc, cursor, bsum);
    scan_top_k<<<1, 128, 0, stream>>>(bsum, boffs);
    scan_fix_k<<<98, 512, 0, stream>>>(cursor, boffs, degc, dinv, rs);
    scatter_k<<<(EE + 255) / 256, 256, 0, stream>>>(ei, cursor, posOf, srcs);

    prep_B<<<132, 256, 0, stream>>>(We2, be2, Bg);
    prep_WT<<<4, 256, 0, stream>>>(Wih, Whh, wta_g, wtb_g);
    prep_edges<<<(EE + 255) / 256, 256, 0, stream>>>(ea, We1, be1, posOf, tmat);
    lin0_k<<<(NN + 255) / 256, 256, 0, stream>>>(x, W0, b0, hf, cur);

    for (int it = 0; it < 3; it++) {
        msg_k<<<512, 512, 0, stream>>>(cur, tmat, srcs, Bg, msgf);
        reduce_k<<<(4 * NN + 255) / 256, 256, 0, stream>>>(msgf, rs, agg);
        node_update_v4<<<(NN + 63) / 64, 512, 0, stream>>>(hf, cur, agg, dinv,
                                                           Wroot, bconv, wta_g, wtb_g, bih, bhh);
    }

    pool_k2<<<49, 256, 0, stream>>>(hf, batch, gsum);
    head_k<<<2, 256, 0, stream>>>(gsum, gcnt, W1a, b1a, W1b, b1b, W2a, b2a, W2b, b2b, dout);
}